// Round 2
// baseline (482.284 us; speedup 1.0000x reference)
//
#include <hip/hip_runtime.h>
#include <math.h>

#define NT 2048       // tokens (B*S)
#define TSLOTS 4096   // token-slots (NT*K)
#define HID 512
#define INTER 2048
#define NE 8
#define TM 64
#define MAXTILES 72   // max sum of ceil(cnt_e/64) <= 4096/64 + 8

// ---------------- workspace layout (bytes) ----------------
#define WS_PROBS     0          // NT*NE floats      = 65536
#define WS_TOPIDX    65536      // TSLOTS ints       = 16384
#define WS_TOPW      81920      // TSLOTS floats     = 16384
#define WS_CNT       98304      // NE ints
#define WS_PSUM      98336      // NE floats
#define WS_CURSOR    98368      // NE ints
#define WS_BASE      98400      // NE ints
#define WS_TILE_E    98432      // MAXTILES ints
#define WS_TILE_B    98720      // MAXTILES ints
#define WS_TILE_V    99008      // MAXTILES ints
#define WS_PERM      99296      // 4608 ints
#define WS_PW        117728     // 4608 floats
#define WS_HMID      1048576    // 4608*INTER floats = 37748736

__device__ __forceinline__ float gelu_tanh(float x) {
    // JAX default: approximate=True
    float x3 = x * x * x;
    return 0.5f * x * (1.0f + tanhf(0.7978845608028654f * (x + 0.044715f * x3)));
}

// -------- router: one wave (64 threads) per token --------
__global__ __launch_bounds__(64) void router_k(
    const float* __restrict__ hs, const float* __restrict__ wr,
    const float* __restrict__ br,
    float* __restrict__ probs, int* __restrict__ topidx, float* __restrict__ topw)
{
    int t = blockIdx.x;
    int lane = threadIdx.x;
    const float* x = hs + (size_t)t * HID;
    float acc[NE];
#pragma unroll
    for (int e = 0; e < NE; e++) acc[e] = 0.0f;
    for (int h = lane; h < HID; h += 64) {
        float xv = x[h];
        const float* w = wr + (size_t)h * NE;
#pragma unroll
        for (int e = 0; e < NE; e++) acc[e] += xv * w[e];
    }
#pragma unroll
    for (int off = 32; off > 0; off >>= 1) {
#pragma unroll
        for (int e = 0; e < NE; e++) acc[e] += __shfl_down(acc[e], off);
    }
    if (lane == 0) {
        float l[NE], p[NE];
        float m = -1e30f;
#pragma unroll
        for (int e = 0; e < NE; e++) { l[e] = acc[e] + br[e]; m = fmaxf(m, l[e]); }
        float s = 0.0f;
#pragma unroll
        for (int e = 0; e < NE; e++) { p[e] = expf(l[e] - m); s += p[e]; }
        float inv = 1.0f / s;
#pragma unroll
        for (int e = 0; e < NE; e++) { p[e] *= inv; probs[(size_t)t * NE + e] = p[e]; }
        // top-2 (ties -> lowest index, matches lax.top_k)
        int i1 = 0;
#pragma unroll
        for (int e = 1; e < NE; e++) if (p[e] > p[i1]) i1 = e;
        int i2 = (i1 == 0) ? 1 : 0;
#pragma unroll
        for (int e = 0; e < NE; e++) if (e != i1 && p[e] > p[i2]) i2 = e;
        float denom = 1.0f / (p[i1] + p[i2]);
        topidx[2 * t]     = i1;
        topidx[2 * t + 1] = i2;
        topw[2 * t]       = p[i1] * denom;
        topw[2 * t + 1]   = p[i2] * denom;
    }
}

// -------- per-expert reductions: counts + prob sums --------
__global__ __launch_bounds__(256) void reduce_k(
    const float* __restrict__ probs, const int* __restrict__ topidx,
    int* __restrict__ cnt, float* __restrict__ psum)
{
    int e = blockIdx.x;
    int tid = threadIdx.x;
    float ps = 0.0f;
    int c = 0;
    for (int t = tid; t < NT; t += 256) ps += probs[(size_t)t * NE + e];
    for (int t = tid; t < TSLOTS; t += 256) c += (topidx[t] == e) ? 1 : 0;
    __shared__ float sps[256];
    __shared__ int sc[256];
    sps[tid] = ps; sc[tid] = c;
    __syncthreads();
    for (int s = 128; s > 0; s >>= 1) {
        if (tid < s) { sps[tid] += sps[tid + s]; sc[tid] += sc[tid + s]; }
        __syncthreads();
    }
    if (tid == 0) { psum[e] = sps[0]; cnt[e] = sc[0]; }
}

// -------- prep: bucket bases, tile map, balance loss --------
__global__ void prep_k(const int* __restrict__ cnt, const float* __restrict__ psum,
                       int* __restrict__ base, int* __restrict__ tile_e,
                       int* __restrict__ tile_b, int* __restrict__ tile_v,
                       float* __restrict__ loss_out)
{
    int b = 0, tidx = 0;
    for (int e = 0; e < NE; e++) {
        int c = cnt[e];
        int nt = (c + TM - 1) / TM;
        base[e] = b;
        for (int i = 0; i < nt; i++) {
            tile_e[tidx] = e;
            tile_b[tidx] = b + i * TM;
            int v = c - i * TM;
            tile_v[tidx] = v > TM ? TM : v;
            tidx++;
        }
        b += nt * TM;
    }
    for (; tidx < MAXTILES; tidx++) tile_e[tidx] = -1;
    float loss = 0.0f;
    for (int e = 0; e < NE; e++)
        loss += ((float)cnt[e] / (float)TSLOTS) * (psum[e] / (float)NT);
    loss_out[0] = 0.01f * (float)NE * loss;
}

// -------- scatter slots into expert buckets --------
__global__ __launch_bounds__(256) void scatter_k(
    const int* __restrict__ topidx, const float* __restrict__ topw,
    const int* __restrict__ base, int* __restrict__ cursor,
    int* __restrict__ perm, float* __restrict__ pw)
{
    int t = blockIdx.x * 256 + threadIdx.x;
    if (t < TSLOTS) {
        int e = topidx[t];
        int p = base[e] + atomicAdd(&cursor[e], 1);
        perm[p] = t;
        pw[p] = topw[t];
    }
}

// -------- residual init: out = hidden_states --------
__global__ __launch_bounds__(256) void copy_k(const float* __restrict__ hs, float* __restrict__ out)
{
    int i = blockIdx.x * 256 + threadIdx.x;
    ((float4*)out)[i] = ((const float4*)hs)[i];
}

// -------- grouped GEMM1: hmid = gelu(gather(x) @ w1[e] + b1[e]) --------
__global__ __launch_bounds__(256) void gemm1_k(
    const float* __restrict__ hs, const float* __restrict__ w1,
    const float* __restrict__ b1,
    const int* __restrict__ tile_e, const int* __restrict__ tile_b,
    const int* __restrict__ tile_v, const int* __restrict__ perm,
    float* __restrict__ hmid)
{
    int tt = blockIdx.y;
    int e = tile_e[tt];
    if (e < 0) return;
    int p0 = tile_b[tt], nv = tile_v[tt];
    int col0 = blockIdx.x * 64;

    __shared__ int rowTok[TM];
    __shared__ float As[TM][17];
    __shared__ float Bs[16][64];

    int tx = threadIdx.x, ty = threadIdx.y;
    int tid = ty * 16 + tx;
    if (tid < TM) {
        int r = tid;
        // padded rows reuse the first valid slot's token (results discarded)
        rowTok[r] = (r < nv) ? (perm[p0 + r] >> 1) : (perm[p0] >> 1);
    }
    __syncthreads();

    int ar = tid >> 2, aseg = tid & 3;
    int bk = tid >> 4, bseg = tid & 15;
    int myTok = rowTok[ar];
    const float* wbase = w1 + (size_t)e * HID * INTER;

    float c[4][4];
#pragma unroll
    for (int i = 0; i < 4; i++)
#pragma unroll
        for (int j = 0; j < 4; j++) c[i][j] = 0.0f;

    for (int k0 = 0; k0 < HID; k0 += 16) {
        float4 av = *(const float4*)(hs + (size_t)myTok * HID + k0 + aseg * 4);
        float4 bv = *(const float4*)(wbase + (size_t)(k0 + bk) * INTER + col0 + bseg * 4);
        As[ar][aseg * 4 + 0] = av.x;
        As[ar][aseg * 4 + 1] = av.y;
        As[ar][aseg * 4 + 2] = av.z;
        As[ar][aseg * 4 + 3] = av.w;
        *(float4*)&Bs[bk][bseg * 4] = bv;
        __syncthreads();
#pragma unroll
        for (int k = 0; k < 16; k++) {
            float a0 = As[ty * 4 + 0][k], a1 = As[ty * 4 + 1][k];
            float a2 = As[ty * 4 + 2][k], a3 = As[ty * 4 + 3][k];
            float b0 = Bs[k][tx * 4 + 0], b1v = Bs[k][tx * 4 + 1];
            float b2v = Bs[k][tx * 4 + 2], b3 = Bs[k][tx * 4 + 3];
            c[0][0] += a0 * b0; c[0][1] += a0 * b1v; c[0][2] += a0 * b2v; c[0][3] += a0 * b3;
            c[1][0] += a1 * b0; c[1][1] += a1 * b1v; c[1][2] += a1 * b2v; c[1][3] += a1 * b3;
            c[2][0] += a2 * b0; c[2][1] += a2 * b1v; c[2][2] += a2 * b2v; c[2][3] += a2 * b3;
            c[3][0] += a3 * b0; c[3][1] += a3 * b1v; c[3][2] += a3 * b2v; c[3][3] += a3 * b3;
        }
        __syncthreads();
    }
#pragma unroll
    for (int i = 0; i < 4; i++) {
        int r = ty * 4 + i;
        if (r < nv) {
            float* dst = hmid + (size_t)(p0 + r) * INTER + col0 + tx * 4;
            const float* bb = b1 + (size_t)e * INTER + col0 + tx * 4;
#pragma unroll
            for (int j = 0; j < 4; j++) dst[j] = gelu_tanh(c[i][j] + bb[j]);
        }
    }
}

// -------- grouped GEMM2: out += weight * (hmid @ w2[e] + b2[e]) --------
__global__ __launch_bounds__(256) void gemm2_k(
    const float* __restrict__ hmid, const float* __restrict__ w2,
    const float* __restrict__ b2,
    const int* __restrict__ tile_e, const int* __restrict__ tile_b,
    const int* __restrict__ tile_v, const int* __restrict__ perm,
    const float* __restrict__ pw, float* __restrict__ out)
{
    int tt = blockIdx.y;
    int e = tile_e[tt];
    if (e < 0) return;
    int p0 = tile_b[tt], nv = tile_v[tt];
    int col0 = blockIdx.x * 64;

    __shared__ float As[TM][17];
    __shared__ float Bs[16][64];

    int tx = threadIdx.x, ty = threadIdx.y;
    int tid = ty * 16 + tx;
    int ar = tid >> 2, aseg = tid & 3;
    int bk = tid >> 4, bseg = tid & 15;
    const float* wbase = w2 + (size_t)e * INTER * HID;

    float c[4][4];
#pragma unroll
    for (int i = 0; i < 4; i++)
#pragma unroll
        for (int j = 0; j < 4; j++) c[i][j] = 0.0f;

    for (int k0 = 0; k0 < INTER; k0 += 16) {
        float4 av = *(const float4*)(hmid + (size_t)(p0 + ar) * INTER + k0 + aseg * 4);
        float4 bv = *(const float4*)(wbase + (size_t)(k0 + bk) * HID + col0 + bseg * 4);
        As[ar][aseg * 4 + 0] = av.x;
        As[ar][aseg * 4 + 1] = av.y;
        As[ar][aseg * 4 + 2] = av.z;
        As[ar][aseg * 4 + 3] = av.w;
        *(float4*)&Bs[bk][bseg * 4] = bv;
        __syncthreads();
#pragma unroll
        for (int k = 0; k < 16; k++) {
            float a0 = As[ty * 4 + 0][k], a1 = As[ty * 4 + 1][k];
            float a2 = As[ty * 4 + 2][k], a3 = As[ty * 4 + 3][k];
            float b0 = Bs[k][tx * 4 + 0], b1v = Bs[k][tx * 4 + 1];
            float b2v = Bs[k][tx * 4 + 2], b3 = Bs[k][tx * 4 + 3];
            c[0][0] += a0 * b0; c[0][1] += a0 * b1v; c[0][2] += a0 * b2v; c[0][3] += a0 * b3;
            c[1][0] += a1 * b0; c[1][1] += a1 * b1v; c[1][2] += a1 * b2v; c[1][3] += a1 * b3;
            c[2][0] += a2 * b0; c[2][1] += a2 * b1v; c[2][2] += a2 * b2v; c[2][3] += a2 * b3;
            c[3][0] += a3 * b0; c[3][1] += a3 * b1v; c[3][2] += a3 * b2v; c[3][3] += a3 * b3;
        }
        __syncthreads();
    }
#pragma unroll
    for (int i = 0; i < 4; i++) {
        int r = ty * 4 + i;
        if (r < nv) {
            int slot = perm[p0 + r];
            int tok = slot >> 1;
            float w = pw[p0 + r];
            float* dst = out + (size_t)tok * HID + col0 + tx * 4;
            const float* bb = b2 + (size_t)e * HID + col0 + tx * 4;
#pragma unroll
            for (int j = 0; j < 4; j++) atomicAdd(&dst[j], w * (c[i][j] + bb[j]));
        }
    }
}

extern "C" void kernel_launch(void* const* d_in, const int* in_sizes, int n_in,
                              void* d_out, int out_size, void* d_ws, size_t ws_size,
                              hipStream_t stream) {
    const float* hs = (const float*)d_in[0];
    const float* wr = (const float*)d_in[1];
    const float* br = (const float*)d_in[2];
    const float* w1 = (const float*)d_in[3];
    const float* b1 = (const float*)d_in[4];
    const float* w2 = (const float*)d_in[5];
    const float* b2 = (const float*)d_in[6];
    float* out = (float*)d_out;

    char* ws = (char*)d_ws;
    float* probs  = (float*)(ws + WS_PROBS);
    int*   topidx = (int*)(ws + WS_TOPIDX);
    float* topw   = (float*)(ws + WS_TOPW);
    int*   cnt    = (int*)(ws + WS_CNT);
    float* psum   = (float*)(ws + WS_PSUM);
    int*   cursor = (int*)(ws + WS_CURSOR);
    int*   base   = (int*)(ws + WS_BASE);
    int*   tile_e = (int*)(ws + WS_TILE_E);
    int*   tile_b = (int*)(ws + WS_TILE_B);
    int*   tile_v = (int*)(ws + WS_TILE_V);
    int*   perm   = (int*)(ws + WS_PERM);
    float* pw     = (float*)(ws + WS_PW);
    float* hmid   = (float*)(ws + WS_HMID);

    (void)hipMemsetAsync(cursor, 0, NE * sizeof(int), stream);

    router_k<<<NT, 64, 0, stream>>>(hs, wr, br, probs, topidx, topw);
    reduce_k<<<NE, 256, 0, stream>>>(probs, topidx, cnt, psum);
    prep_k<<<1, 1, 0, stream>>>(cnt, psum, base, tile_e, tile_b, tile_v,
                                out + (size_t)NT * HID);
    scatter_k<<<TSLOTS / 256, 256, 0, stream>>>(topidx, topw, base, cursor, perm, pw);
    copy_k<<<(NT * HID / 4) / 256, 256, 0, stream>>>(hs, out);
    gemm1_k<<<dim3(INTER / 64, MAXTILES), dim3(16, 16), 0, stream>>>(
        hs, w1, b1, tile_e, tile_b, tile_v, perm, hmid);
    gemm2_k<<<dim3(HID / 64, MAXTILES), dim3(16, 16), 0, stream>>>(
        hmid, w2, b2, tile_e, tile_b, tile_v, perm, pw, out);
}

// Round 3
// 239.008 us; speedup vs baseline: 2.0179x; 2.0179x over previous
//
#include <hip/hip_runtime.h>
#include <math.h>

#define NT 2048       // tokens (B*S)
#define TSLOTS 4096   // token-slots (NT*K)
#define HID 512
#define INTER 2048
#define NE 8
#define TM 128        // row-tile (bucket alignment)
#define BK 32         // k-tile
#define MAXTILES 40   // sum ceil(cnt_e/128) <= 4096/128 + 8

// ---------------- workspace layout (bytes) ----------------
// hmid occupies [0, 20971520); routing scratch overlays its head (all dead
// before gemm1_k writes hmid). wt holds w1t during gemm1, then w2t (re-filled
// after gemm1, before gemm2).
#define WS_HMID      0          // 5120*INTER ushort = 20971520
#define WS_PROBS     0          // NT*NE floats (dead after reduce_k)
#define WS_TOPIDX    65536      // TSLOTS ints  (dead after scatter_k)
#define WS_TOPW      81920      // TSLOTS floats (dead after scatter_k)
#define WS_CNT       98304      // NE ints   (dead after prep_k)
#define WS_PSUM      98336      // NE floats (dead after prep_k)
#define WS_CURSOR    98368      // NE ints   (dead after scatter_k)
#define WS_BASE      98400      // NE ints   (dead after scatter_k)
#define WS_TILE_E    20971520   // MAXTILES ints (live through gemm2)
#define WS_TILE_B    20971776
#define WS_TILE_V    20972032
#define WS_PERM      20972288   // 5120 ints
#define WS_PW        20992768   // 5120 floats
#define WS_XB        21013248   // NT*HID ushort = 2097152
#define WS_WT        23110400   // 8*2048*512 ushort = 16777216 (end ~39.9MB)

typedef __attribute__((ext_vector_type(8))) short bf16x8;
typedef __attribute__((ext_vector_type(4))) float f32x4;

__device__ __forceinline__ unsigned short f2bf(float f) {
    union { float f; unsigned u; } v; v.f = f;
    unsigned r = v.u + 0x7FFF + ((v.u >> 16) & 1);   // RNE
    return (unsigned short)(r >> 16);
}

__device__ __forceinline__ void gload16(const void* g, void* l) {
    __builtin_amdgcn_global_load_lds(
        (const __attribute__((address_space(1))) unsigned int*)g,
        (__attribute__((address_space(3))) unsigned int*)l, 16, 0, 0);
}

__device__ __forceinline__ float gelu_tanh(float x) {
    float x3 = x * x * x;
    return 0.5f * x * (1.0f + tanhf(0.7978845608028654f * (x + 0.044715f * x3)));
}

// -------- router: one wave per token --------
__global__ __launch_bounds__(64) void router_k(
    const float* __restrict__ hs, const float* __restrict__ wr,
    const float* __restrict__ br,
    float* __restrict__ probs, int* __restrict__ topidx, float* __restrict__ topw)
{
    int t = blockIdx.x;
    int lane = threadIdx.x;
    const float* x = hs + (size_t)t * HID;
    float acc[NE];
#pragma unroll
    for (int e = 0; e < NE; e++) acc[e] = 0.0f;
    for (int h = lane; h < HID; h += 64) {
        float xv = x[h];
        const float* w = wr + (size_t)h * NE;
#pragma unroll
        for (int e = 0; e < NE; e++) acc[e] += xv * w[e];
    }
#pragma unroll
    for (int off = 32; off > 0; off >>= 1) {
#pragma unroll
        for (int e = 0; e < NE; e++) acc[e] += __shfl_down(acc[e], off);
    }
    if (lane == 0) {
        float l[NE], p[NE];
        float m = -1e30f;
#pragma unroll
        for (int e = 0; e < NE; e++) { l[e] = acc[e] + br[e]; m = fmaxf(m, l[e]); }
        float s = 0.0f;
#pragma unroll
        for (int e = 0; e < NE; e++) { p[e] = expf(l[e] - m); s += p[e]; }
        float inv = 1.0f / s;
#pragma unroll
        for (int e = 0; e < NE; e++) { p[e] *= inv; probs[(size_t)t * NE + e] = p[e]; }
        int i1 = 0;
#pragma unroll
        for (int e = 1; e < NE; e++) if (p[e] > p[i1]) i1 = e;
        int i2 = (i1 == 0) ? 1 : 0;
#pragma unroll
        for (int e = 0; e < NE; e++) if (e != i1 && p[e] > p[i2]) i2 = e;
        float denom = 1.0f / (p[i1] + p[i2]);
        topidx[2 * t]     = i1;
        topidx[2 * t + 1] = i2;
        topw[2 * t]       = p[i1] * denom;
        topw[2 * t + 1]   = p[i2] * denom;
    }
}

// -------- per-expert reductions --------
__global__ __launch_bounds__(256) void reduce_k(
    const float* __restrict__ probs, const int* __restrict__ topidx,
    int* __restrict__ cnt, float* __restrict__ psum)
{
    int e = blockIdx.x;
    int tid = threadIdx.x;
    float ps = 0.0f;
    int c = 0;
    for (int t = tid; t < NT; t += 256) ps += probs[(size_t)t * NE + e];
    for (int t = tid; t < TSLOTS; t += 256) c += (topidx[t] == e) ? 1 : 0;
    __shared__ float sps[256];
    __shared__ int sc[256];
    sps[tid] = ps; sc[tid] = c;
    __syncthreads();
    for (int s = 128; s > 0; s >>= 1) {
        if (tid < s) { sps[tid] += sps[tid + s]; sc[tid] += sc[tid + s]; }
        __syncthreads();
    }
    if (tid == 0) { psum[e] = sps[0]; cnt[e] = sc[0]; }
}

// -------- prep: bucket bases, tile map (TM=128), balance loss --------
__global__ void prep_k(const int* __restrict__ cnt, const float* __restrict__ psum,
                       int* __restrict__ base, int* __restrict__ tile_e,
                       int* __restrict__ tile_b, int* __restrict__ tile_v,
                       float* __restrict__ loss_out)
{
    int b = 0, tidx = 0;
    for (int e = 0; e < NE; e++) {
        int c = cnt[e];
        int nt = (c + TM - 1) / TM;
        base[e] = b;
        for (int i = 0; i < nt; i++) {
            tile_e[tidx] = e;
            tile_b[tidx] = b + i * TM;
            int v = c - i * TM;
            tile_v[tidx] = v > TM ? TM : v;
            tidx++;
        }
        b += nt * TM;
    }
    for (; tidx < MAXTILES; tidx++) tile_e[tidx] = -1;
    float loss = 0.0f;
    for (int e = 0; e < NE; e++)
        loss += ((float)cnt[e] / (float)TSLOTS) * (psum[e] / (float)NT);
    loss_out[0] = 0.01f * (float)NE * loss;
}

// -------- scatter slots into expert buckets --------
__global__ __launch_bounds__(256) void scatter_k(
    const int* __restrict__ topidx, const float* __restrict__ topw,
    const int* __restrict__ base, int* __restrict__ cursor,
    int* __restrict__ perm, float* __restrict__ pw)
{
    int t = blockIdx.x * 256 + threadIdx.x;
    if (t < TSLOTS) {
        int e = topidx[t];
        int p = base[e] + atomicAdd(&cursor[e], 1);
        perm[p] = t;
        pw[p] = topw[t];
    }
}

// -------- residual init --------
__global__ __launch_bounds__(256) void copy_k(const float* __restrict__ hs, float* __restrict__ out)
{
    int i = blockIdx.x * 256 + threadIdx.x;
    ((float4*)out)[i] = ((const float4*)hs)[i];
}

// -------- convert hs -> bf16 --------
__global__ __launch_bounds__(256) void conv_hs_k(const float* __restrict__ hs,
                                                 unsigned short* __restrict__ xb)
{
    int i = blockIdx.x * 256 + threadIdx.x;
    float4 v = ((const float4*)hs)[i];
    ushort4 o;
    o.x = f2bf(v.x); o.y = f2bf(v.y); o.z = f2bf(v.z); o.w = f2bf(v.w);
    ((ushort4*)xb)[i] = o;
}

// -------- tiled transpose+convert: src[e][K][N] f32 -> dst[e][N][K] bf16 --------
__global__ __launch_bounds__(256) void convT_k(const float* __restrict__ src,
                                               unsigned short* __restrict__ dst,
                                               int K, int N)
{
    int e = blockIdx.z;
    int n0 = blockIdx.x * 32, k0 = blockIdx.y * 32;
    const float* s = src + (size_t)e * K * N;
    unsigned short* d = dst + (size_t)e * N * K;
    __shared__ float T[32][33];
    int tid = threadIdx.x;
    int r = tid >> 3, c4 = (tid & 7) * 4;
    float4 v = *(const float4*)(s + (size_t)(k0 + r) * N + n0 + c4);
    T[r][c4 + 0] = v.x; T[r][c4 + 1] = v.y; T[r][c4 + 2] = v.z; T[r][c4 + 3] = v.w;
    __syncthreads();
    ushort4 o;
    o.x = f2bf(T[c4 + 0][r]); o.y = f2bf(T[c4 + 1][r]);
    o.z = f2bf(T[c4 + 2][r]); o.w = f2bf(T[c4 + 3][r]);
    *(ushort4*)(d + (size_t)(n0 + r) * K + k0 + c4) = o;
}

// ======== grouped MFMA GEMM1: hmid = gelu(gather(xb) @ w1t^T + b1) ========
// A: gathered token rows (bf16, k-contig). B: w1t[e][n][k] (bf16, k-contig).
__global__ __launch_bounds__(256) void gemm1_k(
    const unsigned short* __restrict__ xb, const unsigned short* __restrict__ w1t,
    const float* __restrict__ b1,
    const int* __restrict__ tile_e, const int* __restrict__ tile_b,
    const int* __restrict__ tile_v, const int* __restrict__ perm,
    unsigned short* __restrict__ hmid)
{
    int tt = blockIdx.y;
    int e = tile_e[tt];
    if (e < 0) return;
    int p0 = tile_b[tt], nv = tile_v[tt];
    int n0 = blockIdx.x * 128;

    __shared__ unsigned short As[128 * BK];
    __shared__ unsigned short Bs[128 * BK];

    int tid = threadIdx.x;
    int lane = tid & 63, wave = tid >> 6;
    int wm = (wave >> 1) * 64, wn = (wave & 1) * 64;

    // staging assignment: 4 threads/row, 2 rows/thread
    int r1 = tid >> 2, r2 = 64 + r1;
    int kseg = (tid & 3) * 8;
    int tok1 = perm[p0 + ((r1 < nv) ? r1 : 0)] >> 1;
    int tok2 = perm[p0 + ((r2 < nv) ? r2 : 0)] >> 1;
    const unsigned short* a1p = xb + (size_t)tok1 * HID + kseg;
    const unsigned short* a2p = xb + (size_t)tok2 * HID + kseg;
    const unsigned short* bbase = w1t + (size_t)e * INTER * HID;
    const unsigned short* b1p = bbase + (size_t)(n0 + r1) * HID + kseg;
    const unsigned short* b2p = bbase + (size_t)(n0 + r2) * HID + kseg;

    f32x4 acc[4][4] = {};
    int fm = lane & 15, fq = lane >> 4;

    for (int k0 = 0; k0 < HID; k0 += BK) {
        __syncthreads();
        gload16(a1p + k0, (void*)(As + tid * 8));
        gload16(a2p + k0, (void*)(As + 2048 + tid * 8));
        gload16(b1p + k0, (void*)(Bs + tid * 8));
        gload16(b2p + k0, (void*)(Bs + 2048 + tid * 8));
        __syncthreads();
        bf16x8 af[4], bfr[4];
#pragma unroll
        for (int t = 0; t < 4; t++)
            af[t] = *(const bf16x8*)&As[(wm + t * 16 + fm) * BK + fq * 8];
#pragma unroll
        for (int t = 0; t < 4; t++)
            bfr[t] = *(const bf16x8*)&Bs[(wn + t * 16 + fm) * BK + fq * 8];
#pragma unroll
        for (int mt = 0; mt < 4; mt++)
#pragma unroll
            for (int nt = 0; nt < 4; nt++)
                acc[mt][nt] = __builtin_amdgcn_mfma_f32_16x16x32_bf16(
                    af[mt], bfr[nt], acc[mt][nt], 0, 0, 0);
    }

    // epilogue: C/D layout col=lane&15, row=(lane>>4)*4+reg. Write ALL rows
    // (padded rows = dup of row0's token; gemm2 reads them, discards at store).
    int cn = lane & 15, crb = (lane >> 4) * 4;
#pragma unroll
    for (int mt = 0; mt < 4; mt++) {
#pragma unroll
        for (int r = 0; r < 4; r++) {
            int m = wm + mt * 16 + crb + r;
            size_t rowoff = (size_t)(p0 + m) * INTER;
#pragma unroll
            for (int nt = 0; nt < 4; nt++) {
                int gn = n0 + wn + nt * 16 + cn;
                float vv = acc[mt][nt][r] + b1[e * INTER + gn];
                hmid[rowoff + gn] = f2bf(gelu_tanh(vv));
            }
        }
    }
}

// ======== grouped MFMA GEMM2: out += pw * (hmid @ w2t^T + b2), K-split=2 ========
__global__ __launch_bounds__(256) void gemm2_k(
    const unsigned short* __restrict__ hmid, const unsigned short* __restrict__ w2t,
    const float* __restrict__ b2,
    const int* __restrict__ tile_e, const int* __restrict__ tile_b,
    const int* __restrict__ tile_v, const int* __restrict__ perm,
    const float* __restrict__ pw, float* __restrict__ out)
{
    int tt = blockIdx.y;
    int e = tile_e[tt];
    if (e < 0) return;
    int p0 = tile_b[tt], nv = tile_v[tt];
    int n0 = blockIdx.x * 128;
    int kz = blockIdx.z;
    int kbeg = kz * (INTER / 2), kend = kbeg + INTER / 2;

    __shared__ unsigned short As[128 * BK];
    __shared__ unsigned short Bs[128 * BK];

    int tid = threadIdx.x;
    int lane = tid & 63, wave = tid >> 6;
    int wm = (wave >> 1) * 64, wn = (wave & 1) * 64;

    int r1 = tid >> 2, r2 = 64 + r1;
    int kseg = (tid & 3) * 8;
    const unsigned short* a1p = hmid + (size_t)(p0 + r1) * INTER + kseg;
    const unsigned short* a2p = hmid + (size_t)(p0 + r2) * INTER + kseg;
    const unsigned short* bbase = w2t + (size_t)e * HID * INTER;
    const unsigned short* b1p = bbase + (size_t)(n0 + r1) * INTER + kseg;
    const unsigned short* b2p = bbase + (size_t)(n0 + r2) * INTER + kseg;

    f32x4 acc[4][4] = {};
    int fm = lane & 15, fq = lane >> 4;

    for (int k0 = kbeg; k0 < kend; k0 += BK) {
        __syncthreads();
        gload16(a1p + k0, (void*)(As + tid * 8));
        gload16(a2p + k0, (void*)(As + 2048 + tid * 8));
        gload16(b1p + k0, (void*)(Bs + tid * 8));
        gload16(b2p + k0, (void*)(Bs + 2048 + tid * 8));
        __syncthreads();
        bf16x8 af[4], bfr[4];
#pragma unroll
        for (int t = 0; t < 4; t++)
            af[t] = *(const bf16x8*)&As[(wm + t * 16 + fm) * BK + fq * 8];
#pragma unroll
        for (int t = 0; t < 4; t++)
            bfr[t] = *(const bf16x8*)&Bs[(wn + t * 16 + fm) * BK + fq * 8];
#pragma unroll
        for (int mt = 0; mt < 4; mt++)
#pragma unroll
            for (int nt = 0; nt < 4; nt++)
                acc[mt][nt] = __builtin_amdgcn_mfma_f32_16x16x32_bf16(
                    af[mt], bfr[nt], acc[mt][nt], 0, 0, 0);
    }

    int cn = lane & 15, crb = (lane >> 4) * 4;
#pragma unroll
    for (int mt = 0; mt < 4; mt++) {
#pragma unroll
        for (int r = 0; r < 4; r++) {
            int m = wm + mt * 16 + crb + r;
            if (m < nv) {
                int slot = perm[p0 + m];
                int tok = slot >> 1;
                float w = pw[p0 + m];
                float* dst = out + (size_t)tok * HID;
#pragma unroll
                for (int nt = 0; nt < 4; nt++) {
                    int gn = n0 + wn + nt * 16 + cn;
                    float bias = (kz == 0) ? b2[e * HID + gn] : 0.0f;
                    atomicAdd(&dst[gn], w * (acc[mt][nt][r] + bias));
                }
            }
        }
    }
}

extern "C" void kernel_launch(void* const* d_in, const int* in_sizes, int n_in,
                              void* d_out, int out_size, void* d_ws, size_t ws_size,
                              hipStream_t stream) {
    const float* hs = (const float*)d_in[0];
    const float* wr = (const float*)d_in[1];
    const float* br = (const float*)d_in[2];
    const float* w1 = (const float*)d_in[3];
    const float* b1 = (const float*)d_in[4];
    const float* w2 = (const float*)d_in[5];
    const float* b2 = (const float*)d_in[6];
    float* out = (float*)d_out;

    char* ws = (char*)d_ws;
    float* probs           = (float*)(ws + WS_PROBS);
    int*   topidx          = (int*)(ws + WS_TOPIDX);
    float* topw            = (float*)(ws + WS_TOPW);
    int*   cnt             = (int*)(ws + WS_CNT);
    float* psum            = (float*)(ws + WS_PSUM);
    int*   cursor          = (int*)(ws + WS_CURSOR);
    int*   base            = (int*)(ws + WS_BASE);
    int*   tile_e          = (int*)(ws + WS_TILE_E);
    int*   tile_b          = (int*)(ws + WS_TILE_B);
    int*   tile_v          = (int*)(ws + WS_TILE_V);
    int*   perm            = (int*)(ws + WS_PERM);
    float* pw              = (float*)(ws + WS_PW);
    unsigned short* xb     = (unsigned short*)(ws + WS_XB);
    unsigned short* wt     = (unsigned short*)(ws + WS_WT);
    unsigned short* hmid   = (unsigned short*)(ws + WS_HMID);

    (void)hipMemsetAsync(cursor, 0, NE * sizeof(int), stream);

    router_k<<<NT, 64, 0, stream>>>(hs, wr, br, probs, topidx, topw);
    reduce_k<<<NE, 256, 0, stream>>>(probs, topidx, cnt, psum);
    prep_k<<<1, 1, 0, stream>>>(cnt, psum, base, tile_e, tile_b, tile_v,
                                out + (size_t)NT * HID);
    scatter_k<<<TSLOTS / 256, 256, 0, stream>>>(topidx, topw, base, cursor, perm, pw);
    conv_hs_k<<<(NT * HID / 4) / 256, 256, 0, stream>>>(hs, xb);
    convT_k<<<dim3(INTER / 32, HID / 32, NE), 256, 0, stream>>>(w1, wt, HID, INTER);
    copy_k<<<(NT * HID / 4) / 256, 256, 0, stream>>>(hs, out);
    gemm1_k<<<dim3(INTER / 128, MAXTILES), 256, 0, stream>>>(
        xb, wt, b1, tile_e, tile_b, tile_v, perm, hmid);
    // wt is dead for gemm1 now; refill with w2 transposed
    convT_k<<<dim3(HID / 32, INTER / 32, NE), 256, 0, stream>>>(w2, wt, INTER, HID);
    gemm2_k<<<dim3(HID / 128, MAXTILES, 2), 256, 0, stream>>>(
        hmid, wt, b2, tile_e, tile_b, tile_v, perm, pw, out);
}

// Round 4
// 218.301 us; speedup vs baseline: 2.2093x; 1.0949x over previous
//
#include <hip/hip_runtime.h>
#include <math.h>

#define NT 2048       // tokens (B*S)
#define TSLOTS 4096   // token-slots (NT*K)
#define HID 512
#define INTER 2048
#define NE 8
#define TM 128        // row-tile (bucket alignment)
#define BK 32         // k-tile
#define MAXTILES 40   // sum ceil(cnt_e/128) <= 4096/128 + 8

// ---------------- workspace layout (bytes) ----------------
// hmid occupies [0, 20971520); routing scratch overlays its head (dead before
// gemm1_k writes hmid). wt holds w1t during gemm1, then w2t.
#define WS_HMID      0          // 5120*INTER ushort = 20971520
#define WS_PROBS     0          // NT*NE floats (dead after plan_k)
#define WS_TOPIDX    65536      // TSLOTS ints  (dead after plan_k)
#define WS_TOPW      81920      // TSLOTS floats (dead after plan_k)
#define WS_TILE_E    20971520   // MAXTILES ints (live through gemm2)
#define WS_TILE_B    20971776
#define WS_TILE_V    20972032
#define WS_PERM      20972288   // 5120 ints
#define WS_PW        20992768   // 5120 floats
#define WS_XB        21013248   // NT*HID ushort = 2097152
#define WS_WT        23110400   // 8*2048*512 ushort = 16777216 (end ~39.9MB)

typedef __attribute__((ext_vector_type(8))) short bf16x8;
typedef __attribute__((ext_vector_type(4))) float f32x4;
typedef __attribute__((ext_vector_type(8))) unsigned short ushort8;

__device__ __forceinline__ unsigned short f2bf(float f) {
    union { float f; unsigned u; } v; v.f = f;
    unsigned r = v.u + 0x7FFF + ((v.u >> 16) & 1);   // RNE
    return (unsigned short)(r >> 16);
}

__device__ __forceinline__ void gload16(const void* g, void* l) {
    __builtin_amdgcn_global_load_lds(
        (const __attribute__((address_space(1))) unsigned int*)g,
        (__attribute__((address_space(3))) unsigned int*)l, 16, 0, 0);
}

__device__ __forceinline__ float gelu_tanh(float x) {
    float x3 = x * x * x;
    return 0.5f * x * (1.0f + tanhf(0.7978845608028654f * (x + 0.044715f * x3)));
}

// ======== fused router + bf16 convert + residual copy: one wave per token ====
__global__ __launch_bounds__(64) void route_k(
    const float* __restrict__ hs, const float* __restrict__ wr,
    const float* __restrict__ br,
    unsigned short* __restrict__ xb, float* __restrict__ out,
    float* __restrict__ probs, int* __restrict__ topidx, float* __restrict__ topw)
{
    int t = blockIdx.x;
    int lane = threadIdx.x;
    const float* x = hs + (size_t)t * HID + lane * 8;
    float4 v0 = *(const float4*)x;
    float4 v1 = *(const float4*)(x + 4);

    // residual copy
    float* o = out + (size_t)t * HID + lane * 8;
    *(float4*)o = v0;
    *(float4*)(o + 4) = v1;

    // bf16 convert
    ushort8 ob;
    ob[0] = f2bf(v0.x); ob[1] = f2bf(v0.y); ob[2] = f2bf(v0.z); ob[3] = f2bf(v0.w);
    ob[4] = f2bf(v1.x); ob[5] = f2bf(v1.y); ob[6] = f2bf(v1.z); ob[7] = f2bf(v1.w);
    *(ushort8*)(xb + (size_t)t * HID + lane * 8) = ob;

    // router logits: this lane covers h = lane*8 .. lane*8+7
    float xv[8] = {v0.x, v0.y, v0.z, v0.w, v1.x, v1.y, v1.z, v1.w};
    float acc[NE];
#pragma unroll
    for (int e = 0; e < NE; e++) acc[e] = 0.0f;
    const float* w = wr + (size_t)lane * 8 * NE;
#pragma unroll
    for (int j = 0; j < 8; j++) {
        float4 wa = *(const float4*)(w + j * NE);
        float4 wb = *(const float4*)(w + j * NE + 4);
        acc[0] += xv[j] * wa.x; acc[1] += xv[j] * wa.y;
        acc[2] += xv[j] * wa.z; acc[3] += xv[j] * wa.w;
        acc[4] += xv[j] * wb.x; acc[5] += xv[j] * wb.y;
        acc[6] += xv[j] * wb.z; acc[7] += xv[j] * wb.w;
    }
#pragma unroll
    for (int off = 32; off > 0; off >>= 1) {
#pragma unroll
        for (int e = 0; e < NE; e++) acc[e] += __shfl_down(acc[e], off);
    }
    if (lane == 0) {
        float l[NE], p[NE];
        float m = -1e30f;
#pragma unroll
        for (int e = 0; e < NE; e++) { l[e] = acc[e] + br[e]; m = fmaxf(m, l[e]); }
        float s = 0.0f;
#pragma unroll
        for (int e = 0; e < NE; e++) { p[e] = expf(l[e] - m); s += p[e]; }
        float inv = 1.0f / s;
#pragma unroll
        for (int e = 0; e < NE; e++) { p[e] *= inv; probs[(size_t)t * NE + e] = p[e]; }
        int i1 = 0;
#pragma unroll
        for (int e = 1; e < NE; e++) if (p[e] > p[i1]) i1 = e;
        int i2 = (i1 == 0) ? 1 : 0;
#pragma unroll
        for (int e = 0; e < NE; e++) if (e != i1 && p[e] > p[i2]) i2 = e;
        float denom = 1.0f / (p[i1] + p[i2]);
        topidx[2 * t]     = i1;
        topidx[2 * t + 1] = i2;
        topw[2 * t]       = p[i1] * denom;
        topw[2 * t + 1]   = p[i2] * denom;
    }
}

// ======== plan: reduce + tile map + balance loss + scatter, one workgroup ====
__global__ __launch_bounds__(256) void plan_k(
    const float* __restrict__ probs, const int* __restrict__ topidx,
    const float* __restrict__ topw,
    int* __restrict__ tile_e, int* __restrict__ tile_b, int* __restrict__ tile_v,
    int* __restrict__ perm, float* __restrict__ pw, float* __restrict__ loss_out)
{
    int tid = threadIdx.x;
    int lane = tid & 63, wave = tid >> 6;

    float ps[NE];
    int c[NE];
#pragma unroll
    for (int e = 0; e < NE; e++) { ps[e] = 0.0f; c[e] = 0; }
    for (int t = tid; t < NT; t += 256) {
        float4 p0 = *(const float4*)&probs[(size_t)t * NE];
        float4 p1 = *(const float4*)&probs[(size_t)t * NE + 4];
        ps[0] += p0.x; ps[1] += p0.y; ps[2] += p0.z; ps[3] += p0.w;
        ps[4] += p1.x; ps[5] += p1.y; ps[6] += p1.z; ps[7] += p1.w;
    }
    for (int t = tid; t < TSLOTS; t += 256) c[topidx[t]]++;
#pragma unroll
    for (int off = 32; off > 0; off >>= 1) {
#pragma unroll
        for (int e = 0; e < NE; e++) {
            ps[e] += __shfl_down(ps[e], off);
            c[e]  += __shfl_down(c[e], off);
        }
    }
    __shared__ float sps[4][NE];
    __shared__ int sc[4][NE];
    __shared__ int scur[NE];
    if (lane == 0) {
#pragma unroll
        for (int e = 0; e < NE; e++) { sps[wave][e] = ps[e]; sc[wave][e] = c[e]; }
    }
    __syncthreads();
    if (tid == 0) {
        float loss = 0.0f;
        int b = 0, tidx = 0;
        for (int e = 0; e < NE; e++) {
            float pse = sps[0][e] + sps[1][e] + sps[2][e] + sps[3][e];
            int ce = sc[0][e] + sc[1][e] + sc[2][e] + sc[3][e];
            loss += ((float)ce / (float)TSLOTS) * (pse / (float)NT);
            int nt = (ce + TM - 1) / TM;
            scur[e] = b;
            for (int i = 0; i < nt; i++) {
                tile_e[tidx] = e;
                tile_b[tidx] = b + i * TM;
                int v = ce - i * TM;
                tile_v[tidx] = v > TM ? TM : v;
                tidx++;
            }
            b += nt * TM;
        }
        for (; tidx < MAXTILES; tidx++) tile_e[tidx] = -1;
        loss_out[0] = 0.01f * (float)NE * loss;
    }
    __syncthreads();
    for (int t = tid; t < TSLOTS; t += 256) {
        int e = topidx[t];
        int p = atomicAdd(&scur[e], 1);
        perm[p] = t;
        pw[p] = topw[t];
    }
}

// -------- tiled transpose+convert: src[e][K][N] f32 -> dst[e][N][K] bf16 -----
__global__ __launch_bounds__(256) void convT_k(const float* __restrict__ src,
                                               unsigned short* __restrict__ dst,
                                               int K, int N)
{
    int e = blockIdx.z;
    int n0 = blockIdx.x * 32, k0 = blockIdx.y * 32;
    const float* s = src + (size_t)e * K * N;
    unsigned short* d = dst + (size_t)e * N * K;
    __shared__ float T[32][33];
    int tid = threadIdx.x;
    int r = tid >> 3, c4 = (tid & 7) * 4;
    float4 v = *(const float4*)(s + (size_t)(k0 + r) * N + n0 + c4);
    T[r][c4 + 0] = v.x; T[r][c4 + 1] = v.y; T[r][c4 + 2] = v.z; T[r][c4 + 3] = v.w;
    __syncthreads();
    ushort4 o;
    o.x = f2bf(T[c4 + 0][r]); o.y = f2bf(T[c4 + 1][r]);
    o.z = f2bf(T[c4 + 2][r]); o.w = f2bf(T[c4 + 3][r]);
    *(ushort4*)(d + (size_t)(n0 + r) * K + k0 + c4) = o;
}

// ======== grouped MFMA GEMM1: hmid = gelu(gather(xb) @ w1t^T + b1) ========
__global__ __launch_bounds__(256) void gemm1_k(
    const unsigned short* __restrict__ xb, const unsigned short* __restrict__ w1t,
    const float* __restrict__ b1,
    const int* __restrict__ tile_e, const int* __restrict__ tile_b,
    const int* __restrict__ tile_v, const int* __restrict__ perm,
    unsigned short* __restrict__ hmid)
{
    int tt = blockIdx.y;
    int e = tile_e[tt];
    if (e < 0) return;
    int p0 = tile_b[tt], nv = tile_v[tt];
    int n0 = blockIdx.x * 128;

    __shared__ unsigned short As[128 * BK];
    __shared__ unsigned short Bs[128 * BK];

    int tid = threadIdx.x;
    int lane = tid & 63, wave = tid >> 6;
    int wm = (wave >> 1) * 64, wn = (wave & 1) * 64;

    int r1 = tid >> 2, r2 = 64 + r1;
    int kseg = (tid & 3) * 8;
    int tok1 = perm[p0 + ((r1 < nv) ? r1 : 0)] >> 1;
    int tok2 = perm[p0 + ((r2 < nv) ? r2 : 0)] >> 1;
    const unsigned short* a1p = xb + (size_t)tok1 * HID + kseg;
    const unsigned short* a2p = xb + (size_t)tok2 * HID + kseg;
    const unsigned short* bbase = w1t + (size_t)e * INTER * HID;
    const unsigned short* b1p = bbase + (size_t)(n0 + r1) * HID + kseg;
    const unsigned short* b2p = bbase + (size_t)(n0 + r2) * HID + kseg;

    f32x4 acc[4][4] = {};
    int fm = lane & 15, fq = lane >> 4;

    for (int k0 = 0; k0 < HID; k0 += BK) {
        __syncthreads();
        gload16(a1p + k0, (void*)(As + tid * 8));
        gload16(a2p + k0, (void*)(As + 2048 + tid * 8));
        gload16(b1p + k0, (void*)(Bs + tid * 8));
        gload16(b2p + k0, (void*)(Bs + 2048 + tid * 8));
        __syncthreads();
        bf16x8 af[4], bfr[4];
#pragma unroll
        for (int t = 0; t < 4; t++)
            af[t] = *(const bf16x8*)&As[(wm + t * 16 + fm) * BK + fq * 8];
#pragma unroll
        for (int t = 0; t < 4; t++)
            bfr[t] = *(const bf16x8*)&Bs[(wn + t * 16 + fm) * BK + fq * 8];
#pragma unroll
        for (int mt = 0; mt < 4; mt++)
#pragma unroll
            for (int nt = 0; nt < 4; nt++)
                acc[mt][nt] = __builtin_amdgcn_mfma_f32_16x16x32_bf16(
                    af[mt], bfr[nt], acc[mt][nt], 0, 0, 0);
    }

    int cn = lane & 15, crb = (lane >> 4) * 4;
#pragma unroll
    for (int mt = 0; mt < 4; mt++) {
#pragma unroll
        for (int r = 0; r < 4; r++) {
            int m = wm + mt * 16 + crb + r;
            size_t rowoff = (size_t)(p0 + m) * INTER;
#pragma unroll
            for (int nt = 0; nt < 4; nt++) {
                int gn = n0 + wn + nt * 16 + cn;
                float vv = acc[mt][nt][r] + b1[e * INTER + gn];
                hmid[rowoff + gn] = f2bf(gelu_tanh(vv));
            }
        }
    }
}

// ======== grouped MFMA GEMM2: out += pw * (hmid @ w2t^T + b2), K-split=4 =====
__global__ __launch_bounds__(256) void gemm2_k(
    const unsigned short* __restrict__ hmid, const unsigned short* __restrict__ w2t,
    const float* __restrict__ b2,
    const int* __restrict__ tile_e, const int* __restrict__ tile_b,
    const int* __restrict__ tile_v, const int* __restrict__ perm,
    const float* __restrict__ pw, float* __restrict__ out)
{
    int tt = blockIdx.y;
    int e = tile_e[tt];
    if (e < 0) return;
    int p0 = tile_b[tt], nv = tile_v[tt];
    int n0 = blockIdx.x * 128;
    int kz = blockIdx.z;
    int kbeg = kz * (INTER / 4), kend = kbeg + INTER / 4;

    __shared__ unsigned short As[128 * BK];
    __shared__ unsigned short Bs[128 * BK];

    int tid = threadIdx.x;
    int lane = tid & 63, wave = tid >> 6;
    int wm = (wave >> 1) * 64, wn = (wave & 1) * 64;

    int r1 = tid >> 2, r2 = 64 + r1;
    int kseg = (tid & 3) * 8;
    const unsigned short* a1p = hmid + (size_t)(p0 + r1) * INTER + kseg;
    const unsigned short* a2p = hmid + (size_t)(p0 + r2) * INTER + kseg;
    const unsigned short* bbase = w2t + (size_t)e * HID * INTER;
    const unsigned short* b1p = bbase + (size_t)(n0 + r1) * INTER + kseg;
    const unsigned short* b2p = bbase + (size_t)(n0 + r2) * INTER + kseg;

    f32x4 acc[4][4] = {};
    int fm = lane & 15, fq = lane >> 4;

    for (int k0 = kbeg; k0 < kend; k0 += BK) {
        __syncthreads();
        gload16(a1p + k0, (void*)(As + tid * 8));
        gload16(a2p + k0, (void*)(As + 2048 + tid * 8));
        gload16(b1p + k0, (void*)(Bs + tid * 8));
        gload16(b2p + k0, (void*)(Bs + 2048 + tid * 8));
        __syncthreads();
        bf16x8 af[4], bfr[4];
#pragma unroll
        for (int t = 0; t < 4; t++)
            af[t] = *(const bf16x8*)&As[(wm + t * 16 + fm) * BK + fq * 8];
#pragma unroll
        for (int t = 0; t < 4; t++)
            bfr[t] = *(const bf16x8*)&Bs[(wn + t * 16 + fm) * BK + fq * 8];
#pragma unroll
        for (int mt = 0; mt < 4; mt++)
#pragma unroll
            for (int nt = 0; nt < 4; nt++)
                acc[mt][nt] = __builtin_amdgcn_mfma_f32_16x16x32_bf16(
                    af[mt], bfr[nt], acc[mt][nt], 0, 0, 0);
    }

    int cn = lane & 15, crb = (lane >> 4) * 4;
#pragma unroll
    for (int mt = 0; mt < 4; mt++) {
#pragma unroll
        for (int r = 0; r < 4; r++) {
            int m = wm + mt * 16 + crb + r;
            if (m < nv) {
                int slot = perm[p0 + m];
                int tok = slot >> 1;
                float w = pw[p0 + m];
                float* dst = out + (size_t)tok * HID;
#pragma unroll
                for (int nt = 0; nt < 4; nt++) {
                    int gn = n0 + wn + nt * 16 + cn;
                    float bias = (kz == 0) ? b2[e * HID + gn] : 0.0f;
                    atomicAdd(&dst[gn], w * (acc[mt][nt][r] + bias));
                }
            }
        }
    }
}

extern "C" void kernel_launch(void* const* d_in, const int* in_sizes, int n_in,
                              void* d_out, int out_size, void* d_ws, size_t ws_size,
                              hipStream_t stream) {
    const float* hs = (const float*)d_in[0];
    const float* wr = (const float*)d_in[1];
    const float* br = (const float*)d_in[2];
    const float* w1 = (const float*)d_in[3];
    const float* b1 = (const float*)d_in[4];
    const float* w2 = (const float*)d_in[5];
    const float* b2 = (const float*)d_in[6];
    float* out = (float*)d_out;

    char* ws = (char*)d_ws;
    float* probs           = (float*)(ws + WS_PROBS);
    int*   topidx          = (int*)(ws + WS_TOPIDX);
    float* topw            = (float*)(ws + WS_TOPW);
    int*   tile_e          = (int*)(ws + WS_TILE_E);
    int*   tile_b          = (int*)(ws + WS_TILE_B);
    int*   tile_v          = (int*)(ws + WS_TILE_V);
    int*   perm            = (int*)(ws + WS_PERM);
    float* pw              = (float*)(ws + WS_PW);
    unsigned short* xb     = (unsigned short*)(ws + WS_XB);
    unsigned short* wt     = (unsigned short*)(ws + WS_WT);
    unsigned short* hmid   = (unsigned short*)(ws + WS_HMID);

    route_k<<<NT, 64, 0, stream>>>(hs, wr, br, xb, out, probs, topidx, topw);
    plan_k<<<1, 256, 0, stream>>>(probs, topidx, topw, tile_e, tile_b, tile_v,
                                  perm, pw, out + (size_t)NT * HID);
    convT_k<<<dim3(INTER / 32, HID / 32, NE), 256, 0, stream>>>(w1, wt, HID, INTER);
    gemm1_k<<<dim3(INTER / 128, MAXTILES), 256, 0, stream>>>(
        xb, wt, b1, tile_e, tile_b, tile_v, perm, hmid);
    convT_k<<<dim3(HID / 32, INTER / 32, NE), 256, 0, stream>>>(w2, wt, INTER, HID);
    gemm2_k<<<dim3(HID / 128, MAXTILES, 4), 256, 0, stream>>>(
        hmid, wt, b2, tile_e, tile_b, tile_v, perm, pw, out);
}

// Round 5
// 211.676 us; speedup vs baseline: 2.2784x; 1.0313x over previous
//
#include <hip/hip_runtime.h>
#include <math.h>

#define NT 2048       // tokens (B*S)
#define TSLOTS 4096   // token-slots (NT*K)
#define HID 512
#define INTER 2048
#define NE 8
#define TM 128        // row-tile (bucket alignment)
#define BK 32         // k-tile
#define MAXTILES 40   // sum ceil(cnt_e/128) <= 4096/128 + 8
#define PSLOTS 5120   // padded slot capacity

// ---------------- workspace layout (bytes) ----------------
#define WS_HMID      0          // PSLOTS*INTER ushort = 20971520
#define WS_PROBS     0          // NT*NE floats (dead after plan_k)
#define WS_TOPIDX    65536      // TSLOTS ints  (dead after plan_k)
#define WS_TOPW      81920      // TSLOTS floats (dead after plan_k)
#define WS_TILE_E    20971520
#define WS_TILE_B    20971776
#define WS_TILE_V    20972032
#define WS_PERM      20972288   // PSLOTS ints
#define WS_PW        20992768   // PSLOTS floats
#define WS_ISLOT     21013248   // TSLOTS ints
#define WS_XB        21029632   // NT*HID ushort = 2097152
#define WS_WT        23126784   // 8*2048*512 ushort = 16777216
#define WS_Y         39904000   // 2 * PSLOTS*HID ushort = 10485760 (end ~50.4MB)

typedef __attribute__((ext_vector_type(8))) short bf16x8;
typedef __attribute__((ext_vector_type(4))) float f32x4;
typedef __attribute__((ext_vector_type(8))) unsigned short ushort8;

__device__ __forceinline__ unsigned short f2bf(float f) {
    union { float f; unsigned u; } v; v.f = f;
    unsigned r = v.u + 0x7FFF + ((v.u >> 16) & 1);   // RNE
    return (unsigned short)(r >> 16);
}
__device__ __forceinline__ float bf2f(unsigned short b) {
    union { unsigned u; float f; } v; v.u = ((unsigned)b) << 16;
    return v.f;
}

__device__ __forceinline__ void gload16(const void* g, void* l) {
    __builtin_amdgcn_global_load_lds(
        (const __attribute__((address_space(1))) unsigned int*)g,
        (__attribute__((address_space(3))) unsigned int*)l, 16, 0, 0);
}

__device__ __forceinline__ float gelu_tanh(float x) {
    float x3 = x * x * x;
    return 0.5f * x * (1.0f + tanhf(0.7978845608028654f * (x + 0.044715f * x3)));
}

// ======== fused router + bf16 convert: one wave per token ====
__global__ __launch_bounds__(64) void route_k(
    const float* __restrict__ hs, const float* __restrict__ wr,
    const float* __restrict__ br,
    unsigned short* __restrict__ xb,
    float* __restrict__ probs, int* __restrict__ topidx, float* __restrict__ topw)
{
    int t = blockIdx.x;
    int lane = threadIdx.x;
    const float* x = hs + (size_t)t * HID + lane * 8;
    float4 v0 = *(const float4*)x;
    float4 v1 = *(const float4*)(x + 4);

    ushort8 ob;
    ob[0] = f2bf(v0.x); ob[1] = f2bf(v0.y); ob[2] = f2bf(v0.z); ob[3] = f2bf(v0.w);
    ob[4] = f2bf(v1.x); ob[5] = f2bf(v1.y); ob[6] = f2bf(v1.z); ob[7] = f2bf(v1.w);
    *(ushort8*)(xb + (size_t)t * HID + lane * 8) = ob;

    float xv[8] = {v0.x, v0.y, v0.z, v0.w, v1.x, v1.y, v1.z, v1.w};
    float acc[NE];
#pragma unroll
    for (int e = 0; e < NE; e++) acc[e] = 0.0f;
    const float* w = wr + (size_t)lane * 8 * NE;
#pragma unroll
    for (int j = 0; j < 8; j++) {
        float4 wa = *(const float4*)(w + j * NE);
        float4 wb = *(const float4*)(w + j * NE + 4);
        acc[0] += xv[j] * wa.x; acc[1] += xv[j] * wa.y;
        acc[2] += xv[j] * wa.z; acc[3] += xv[j] * wa.w;
        acc[4] += xv[j] * wb.x; acc[5] += xv[j] * wb.y;
        acc[6] += xv[j] * wb.z; acc[7] += xv[j] * wb.w;
    }
#pragma unroll
    for (int off = 32; off > 0; off >>= 1) {
#pragma unroll
        for (int e = 0; e < NE; e++) acc[e] += __shfl_down(acc[e], off);
    }
    if (lane == 0) {
        float l[NE], p[NE];
        float m = -1e30f;
#pragma unroll
        for (int e = 0; e < NE; e++) { l[e] = acc[e] + br[e]; m = fmaxf(m, l[e]); }
        float s = 0.0f;
#pragma unroll
        for (int e = 0; e < NE; e++) { p[e] = expf(l[e] - m); s += p[e]; }
        float inv = 1.0f / s;
#pragma unroll
        for (int e = 0; e < NE; e++) { p[e] *= inv; probs[(size_t)t * NE + e] = p[e]; }
        int i1 = 0;
#pragma unroll
        for (int e = 1; e < NE; e++) if (p[e] > p[i1]) i1 = e;
        int i2 = (i1 == 0) ? 1 : 0;
#pragma unroll
        for (int e = 0; e < NE; e++) if (e != i1 && p[e] > p[i2]) i2 = e;
        float denom = 1.0f / (p[i1] + p[i2]);
        topidx[2 * t]     = i1;
        topidx[2 * t + 1] = i2;
        topw[2 * t]       = p[i1] * denom;
        topw[2 * t + 1]   = p[i2] * denom;
    }
}

// ======== plan: reduce + tile map + loss + scatter (+inverse perm) ====
__global__ __launch_bounds__(256) void plan_k(
    const float* __restrict__ probs, const int* __restrict__ topidx,
    const float* __restrict__ topw,
    int* __restrict__ tile_e, int* __restrict__ tile_b, int* __restrict__ tile_v,
    int* __restrict__ perm, float* __restrict__ pw, int* __restrict__ islot,
    float* __restrict__ loss_out)
{
    int tid = threadIdx.x;
    int lane = tid & 63, wave = tid >> 6;

    float ps[NE];
    int c[NE];
#pragma unroll
    for (int e = 0; e < NE; e++) { ps[e] = 0.0f; c[e] = 0; }
    for (int t = tid; t < NT; t += 256) {
        float4 p0 = *(const float4*)&probs[(size_t)t * NE];
        float4 p1 = *(const float4*)&probs[(size_t)t * NE + 4];
        ps[0] += p0.x; ps[1] += p0.y; ps[2] += p0.z; ps[3] += p0.w;
        ps[4] += p1.x; ps[5] += p1.y; ps[6] += p1.z; ps[7] += p1.w;
    }
    for (int t = tid; t < TSLOTS; t += 256) c[topidx[t]]++;
#pragma unroll
    for (int off = 32; off > 0; off >>= 1) {
#pragma unroll
        for (int e = 0; e < NE; e++) {
            ps[e] += __shfl_down(ps[e], off);
            c[e]  += __shfl_down(c[e], off);
        }
    }
    __shared__ float sps[4][NE];
    __shared__ int sc[4][NE];
    __shared__ int scur[NE];
    if (lane == 0) {
#pragma unroll
        for (int e = 0; e < NE; e++) { sps[wave][e] = ps[e]; sc[wave][e] = c[e]; }
    }
    __syncthreads();
    if (tid == 0) {
        float loss = 0.0f;
        int b = 0, tidx = 0;
        for (int e = 0; e < NE; e++) {
            float pse = sps[0][e] + sps[1][e] + sps[2][e] + sps[3][e];
            int ce = sc[0][e] + sc[1][e] + sc[2][e] + sc[3][e];
            loss += ((float)ce / (float)TSLOTS) * (pse / (float)NT);
            int nt = (ce + TM - 1) / TM;
            scur[e] = b;
            for (int i = 0; i < nt; i++) {
                tile_e[tidx] = e;
                tile_b[tidx] = b + i * TM;
                int v = ce - i * TM;
                tile_v[tidx] = v > TM ? TM : v;
                tidx++;
            }
            b += nt * TM;
        }
        for (; tidx < MAXTILES; tidx++) tile_e[tidx] = -1;
        loss_out[0] = 0.01f * (float)NE * loss;
    }
    __syncthreads();
    for (int t = tid; t < TSLOTS; t += 256) {
        int e = topidx[t];
        int p = atomicAdd(&scur[e], 1);
        perm[p] = t;
        pw[p] = topw[t];
        islot[t] = p;
    }
}

// -------- tiled transpose+convert: src[e][K][N] f32 -> dst[e][N][K] bf16 -----
__global__ __launch_bounds__(256) void convT_k(const float* __restrict__ src,
                                               unsigned short* __restrict__ dst,
                                               int K, int N)
{
    int e = blockIdx.z;
    int n0 = blockIdx.x * 32, k0 = blockIdx.y * 32;
    const float* s = src + (size_t)e * K * N;
    unsigned short* d = dst + (size_t)e * N * K;
    __shared__ float T[32][33];
    int tid = threadIdx.x;
    int r = tid >> 3, c4 = (tid & 7) * 4;
    float4 v = *(const float4*)(s + (size_t)(k0 + r) * N + n0 + c4);
    T[r][c4 + 0] = v.x; T[r][c4 + 1] = v.y; T[r][c4 + 2] = v.z; T[r][c4 + 3] = v.w;
    __syncthreads();
    ushort4 o;
    o.x = f2bf(T[c4 + 0][r]); o.y = f2bf(T[c4 + 1][r]);
    o.z = f2bf(T[c4 + 2][r]); o.w = f2bf(T[c4 + 3][r]);
    *(ushort4*)(d + (size_t)(n0 + r) * K + k0 + c4) = o;
}

// ======== grouped MFMA GEMM1: hmid = gelu(gather(xb) @ w1t^T + b1) ========
__global__ __launch_bounds__(256) void gemm1_k(
    const unsigned short* __restrict__ xb, const unsigned short* __restrict__ w1t,
    const float* __restrict__ b1,
    const int* __restrict__ tile_e, const int* __restrict__ tile_b,
    const int* __restrict__ tile_v, const int* __restrict__ perm,
    unsigned short* __restrict__ hmid)
{
    int tt = blockIdx.y;
    int e = tile_e[tt];
    if (e < 0) return;
    int p0 = tile_b[tt], nv = tile_v[tt];
    int n0 = blockIdx.x * 128;

    __shared__ unsigned short As[128 * BK];
    __shared__ unsigned short Bs[128 * BK];

    int tid = threadIdx.x;
    int lane = tid & 63, wave = tid >> 6;
    int wm = (wave >> 1) * 64, wn = (wave & 1) * 64;

    int r1 = tid >> 2, r2 = 64 + r1;
    int kseg = (tid & 3) * 8;
    int tok1 = perm[p0 + ((r1 < nv) ? r1 : 0)] >> 1;
    int tok2 = perm[p0 + ((r2 < nv) ? r2 : 0)] >> 1;
    const unsigned short* a1p = xb + (size_t)tok1 * HID + kseg;
    const unsigned short* a2p = xb + (size_t)tok2 * HID + kseg;
    const unsigned short* bbase = w1t + (size_t)e * INTER * HID;
    const unsigned short* b1p = bbase + (size_t)(n0 + r1) * HID + kseg;
    const unsigned short* b2p = bbase + (size_t)(n0 + r2) * HID + kseg;

    f32x4 acc[4][4] = {};
    int fm = lane & 15, fq = lane >> 4;

    for (int k0 = 0; k0 < HID; k0 += BK) {
        __syncthreads();
        gload16(a1p + k0, (void*)(As + tid * 8));
        gload16(a2p + k0, (void*)(As + 2048 + tid * 8));
        gload16(b1p + k0, (void*)(Bs + tid * 8));
        gload16(b2p + k0, (void*)(Bs + 2048 + tid * 8));
        __syncthreads();
        bf16x8 af[4], bfr[4];
#pragma unroll
        for (int t = 0; t < 4; t++)
            af[t] = *(const bf16x8*)&As[(wm + t * 16 + fm) * BK + fq * 8];
#pragma unroll
        for (int t = 0; t < 4; t++)
            bfr[t] = *(const bf16x8*)&Bs[(wn + t * 16 + fm) * BK + fq * 8];
#pragma unroll
        for (int mt = 0; mt < 4; mt++)
#pragma unroll
            for (int nt = 0; nt < 4; nt++)
                acc[mt][nt] = __builtin_amdgcn_mfma_f32_16x16x32_bf16(
                    af[mt], bfr[nt], acc[mt][nt], 0, 0, 0);
    }

    int cn = lane & 15, crb = (lane >> 4) * 4;
#pragma unroll
    for (int mt = 0; mt < 4; mt++) {
#pragma unroll
        for (int r = 0; r < 4; r++) {
            int m = wm + mt * 16 + crb + r;
            size_t rowoff = (size_t)(p0 + m) * INTER;
#pragma unroll
            for (int nt = 0; nt < 4; nt++) {
                int gn = n0 + wn + nt * 16 + cn;
                float vv = acc[mt][nt][r] + b1[e * INTER + gn];
                hmid[rowoff + gn] = f2bf(gelu_tanh(vv));
            }
        }
    }
}

// ======== grouped MFMA GEMM2: y[kz][slot] = hmid @ w2t^T (+b2), no atomics ===
// 128x64 tile, kz in {0,1} halves K. Plain bf16 stores; padded rows harmless.
__global__ __launch_bounds__(256) void gemm2_k(
    const unsigned short* __restrict__ hmid, const unsigned short* __restrict__ w2t,
    const float* __restrict__ b2,
    const int* __restrict__ tile_e, const int* __restrict__ tile_b,
    unsigned short* __restrict__ y)
{
    int tt = blockIdx.y;
    int e = tile_e[tt];
    if (e < 0) return;
    int p0 = tile_b[tt];
    int n0 = blockIdx.x * 64;
    int kz = blockIdx.z;
    int kbeg = kz * (INTER / 2), kend = kbeg + INTER / 2;
    unsigned short* yk = y + (size_t)kz * PSLOTS * HID;

    __shared__ unsigned short As[128 * BK];   // 8 KB
    __shared__ unsigned short Bs[64 * BK];    // 4 KB

    int tid = threadIdx.x;
    int lane = tid & 63, wave = tid >> 6;
    int wm = (wave >> 1) * 64, wn = (wave & 1) * 32;

    int r1 = tid >> 2, r2 = 64 + r1;
    int kseg = (tid & 3) * 8;
    const unsigned short* a1p = hmid + (size_t)(p0 + r1) * INTER + kseg;
    const unsigned short* a2p = hmid + (size_t)(p0 + r2) * INTER + kseg;
    const unsigned short* bbase = w2t + (size_t)e * HID * INTER;
    const unsigned short* bp = bbase + (size_t)(n0 + r1) * INTER + kseg;

    f32x4 acc[4][2] = {};
    int fm = lane & 15, fq = lane >> 4;

    for (int k0 = kbeg; k0 < kend; k0 += BK) {
        __syncthreads();
        gload16(a1p + k0, (void*)(As + tid * 8));
        gload16(a2p + k0, (void*)(As + 2048 + tid * 8));
        gload16(bp + k0, (void*)(Bs + tid * 8));
        __syncthreads();
        bf16x8 af[4], bfr[2];
#pragma unroll
        for (int t = 0; t < 4; t++)
            af[t] = *(const bf16x8*)&As[(wm + t * 16 + fm) * BK + fq * 8];
#pragma unroll
        for (int t = 0; t < 2; t++)
            bfr[t] = *(const bf16x8*)&Bs[(wn + t * 16 + fm) * BK + fq * 8];
#pragma unroll
        for (int mt = 0; mt < 4; mt++)
#pragma unroll
            for (int nt = 0; nt < 2; nt++)
                acc[mt][nt] = __builtin_amdgcn_mfma_f32_16x16x32_bf16(
                    af[mt], bfr[nt], acc[mt][nt], 0, 0, 0);
    }

    int cn = lane & 15, crb = (lane >> 4) * 4;
#pragma unroll
    for (int mt = 0; mt < 4; mt++) {
#pragma unroll
        for (int r = 0; r < 4; r++) {
            int m = wm + mt * 16 + crb + r;
            size_t rowoff = (size_t)(p0 + m) * HID;
#pragma unroll
            for (int nt = 0; nt < 2; nt++) {
                int gn = n0 + wn + nt * 16 + cn;
                float bias = (kz == 0) ? b2[e * HID + gn] : 0.0f;
                yk[rowoff + gn] = f2bf(acc[mt][nt][r] + bias);
            }
        }
    }
}

// ======== combine: out = hs + wA*(y0[pA]+y1[pA]) + wB*(y0[pB]+y1[pB]) ========
__global__ __launch_bounds__(64) void combine_k(
    const float* __restrict__ hs, const unsigned short* __restrict__ y,
    const int* __restrict__ islot, const float* __restrict__ pw,
    float* __restrict__ out)
{
    int t = blockIdx.x;
    int lane = threadIdx.x;
    int pA = islot[2 * t], pB = islot[2 * t + 1];
    float wA = pw[pA], wB = pw[pB];
    int c = lane * 8;
    const unsigned short* yA0 = y + (size_t)pA * HID + c;
    const unsigned short* yB0 = y + (size_t)pB * HID + c;
    const unsigned short* yA1 = yA0 + (size_t)PSLOTS * HID;
    const unsigned short* yB1 = yB0 + (size_t)PSLOTS * HID;
    ushort8 a0 = *(const ushort8*)yA0;
    ushort8 a1 = *(const ushort8*)yA1;
    ushort8 b0 = *(const ushort8*)yB0;
    ushort8 b1 = *(const ushort8*)yB1;
    const float* h = hs + (size_t)t * HID + c;
    float4 h0 = *(const float4*)h;
    float4 h1 = *(const float4*)(h + 4);
    float o[8];
#pragma unroll
    for (int j = 0; j < 8; j++)
        o[j] = wA * (bf2f(a0[j]) + bf2f(a1[j])) + wB * (bf2f(b0[j]) + bf2f(b1[j]));
    float4 r0 = {o[0] + h0.x, o[1] + h0.y, o[2] + h0.z, o[3] + h0.w};
    float4 r1 = {o[4] + h1.x, o[5] + h1.y, o[6] + h1.z, o[7] + h1.w};
    float* op = out + (size_t)t * HID + c;
    *(float4*)op = r0;
    *(float4*)(op + 4) = r1;
}

extern "C" void kernel_launch(void* const* d_in, const int* in_sizes, int n_in,
                              void* d_out, int out_size, void* d_ws, size_t ws_size,
                              hipStream_t stream) {
    const float* hs = (const float*)d_in[0];
    const float* wr = (const float*)d_in[1];
    const float* br = (const float*)d_in[2];
    const float* w1 = (const float*)d_in[3];
    const float* b1 = (const float*)d_in[4];
    const float* w2 = (const float*)d_in[5];
    const float* b2 = (const float*)d_in[6];
    float* out = (float*)d_out;

    char* ws = (char*)d_ws;
    float* probs           = (float*)(ws + WS_PROBS);
    int*   topidx          = (int*)(ws + WS_TOPIDX);
    float* topw            = (float*)(ws + WS_TOPW);
    int*   tile_e          = (int*)(ws + WS_TILE_E);
    int*   tile_b          = (int*)(ws + WS_TILE_B);
    int*   tile_v          = (int*)(ws + WS_TILE_V);
    int*   perm            = (int*)(ws + WS_PERM);
    float* pw              = (float*)(ws + WS_PW);
    int*   islot           = (int*)(ws + WS_ISLOT);
    unsigned short* xb     = (unsigned short*)(ws + WS_XB);
    unsigned short* wt     = (unsigned short*)(ws + WS_WT);
    unsigned short* hmid   = (unsigned short*)(ws + WS_HMID);
    unsigned short* y      = (unsigned short*)(ws + WS_Y);

    route_k<<<NT, 64, 0, stream>>>(hs, wr, br, xb, probs, topidx, topw);
    plan_k<<<1, 256, 0, stream>>>(probs, topidx, topw, tile_e, tile_b, tile_v,
                                  perm, pw, islot, out + (size_t)NT * HID);
    convT_k<<<dim3(INTER / 32, HID / 32, NE), 256, 0, stream>>>(w1, wt, HID, INTER);
    gemm1_k<<<dim3(INTER / 128, MAXTILES), 256, 0, stream>>>(
        xb, wt, b1, tile_e, tile_b, tile_v, perm, hmid);
    convT_k<<<dim3(HID / 32, INTER / 32, NE), 256, 0, stream>>>(w2, wt, INTER, HID);
    gemm2_k<<<dim3(HID / 64, MAXTILES, 2), 256, 0, stream>>>(
        hmid, wt, b2, tile_e, tile_b, y);
    combine_k<<<NT, 64, 0, stream>>>(hs, y, islot, pw, out);
}

// Round 6
// 193.006 us; speedup vs baseline: 2.4988x; 1.0967x over previous
//
#include <hip/hip_runtime.h>
#include <math.h>

#define NT 2048       // tokens (B*S)
#define TSLOTS 4096   // token-slots (NT*K)
#define HID 512
#define INTER 2048
#define NE 8
#define TM 64         // row-tile (bucket alignment)
#define BKG 64        // k-tile
#define MAXTILES 72   // sum ceil(cnt_e/64) <= 4096/64 + 7
#define PSLOTS 4608   // padded slot capacity

// ---------------- workspace layout (bytes) ----------------
#define WS_HMID      0          // PSLOTS*INTER ushort = 18874368
#define WS_PROBS     0          // NT*NE floats (dead after plan_k)
#define WS_TOPIDX    65536      // TSLOTS ints  (dead after plan_k)
#define WS_TOPW      81920      // TSLOTS floats (dead after plan_k)
#define WS_TILE_E    18874368
#define WS_TILE_B    18874880
#define WS_TILE_V    18875392
#define WS_PERM      18875904   // PSLOTS ints = 18432
#define WS_PW        18894336   // PSLOTS floats
#define WS_ISLOT     18912768   // TSLOTS ints
#define WS_XB        18929152   // NT*HID ushort = 2097152
#define WS_WT        21026304   // 8*2048*512 ushort = 16777216
#define WS_Y         37803520   // 2 * PSLOTS*HID ushort = 9437184 (end ~47.2MB)

typedef __attribute__((ext_vector_type(8))) short bf16x8;
typedef __attribute__((ext_vector_type(4))) float f32x4;
typedef __attribute__((ext_vector_type(8))) unsigned short ushort8;

__device__ __forceinline__ unsigned short f2bf(float f) {
    union { float f; unsigned u; } v; v.f = f;
    unsigned r = v.u + 0x7FFF + ((v.u >> 16) & 1);   // RNE
    return (unsigned short)(r >> 16);
}
__device__ __forceinline__ float bf2f(unsigned short b) {
    union { unsigned u; float f; } v; v.u = ((unsigned)b) << 16;
    return v.f;
}

__device__ __forceinline__ void gload16(const void* g, void* l) {
    __builtin_amdgcn_global_load_lds(
        (const __attribute__((address_space(1))) unsigned int*)g,
        (__attribute__((address_space(3))) unsigned int*)l, 16, 0, 0);
}

// gelu_tanh(x) == x * sigmoid(2*0.7978845608*(x + 0.044715 x^3))  (exact identity)
__device__ __forceinline__ float gelu_fast(float x) {
    float t = 1.5957691f * x + 0.0713548f * x * x * x;
    return x / (1.0f + __expf(-t));
}

// ======== fused router + bf16 convert: one wave per token ====
__global__ __launch_bounds__(64) void route_k(
    const float* __restrict__ hs, const float* __restrict__ wr,
    const float* __restrict__ br,
    unsigned short* __restrict__ xb,
    float* __restrict__ probs, int* __restrict__ topidx, float* __restrict__ topw)
{
    int t = blockIdx.x;
    int lane = threadIdx.x;
    const float* x = hs + (size_t)t * HID + lane * 8;
    float4 v0 = *(const float4*)x;
    float4 v1 = *(const float4*)(x + 4);

    ushort8 ob;
    ob[0] = f2bf(v0.x); ob[1] = f2bf(v0.y); ob[2] = f2bf(v0.z); ob[3] = f2bf(v0.w);
    ob[4] = f2bf(v1.x); ob[5] = f2bf(v1.y); ob[6] = f2bf(v1.z); ob[7] = f2bf(v1.w);
    *(ushort8*)(xb + (size_t)t * HID + lane * 8) = ob;

    float xv[8] = {v0.x, v0.y, v0.z, v0.w, v1.x, v1.y, v1.z, v1.w};
    float acc[NE];
#pragma unroll
    for (int e = 0; e < NE; e++) acc[e] = 0.0f;
    const float* w = wr + (size_t)lane * 8 * NE;
#pragma unroll
    for (int j = 0; j < 8; j++) {
        float4 wa = *(const float4*)(w + j * NE);
        float4 wb = *(const float4*)(w + j * NE + 4);
        acc[0] += xv[j] * wa.x; acc[1] += xv[j] * wa.y;
        acc[2] += xv[j] * wa.z; acc[3] += xv[j] * wa.w;
        acc[4] += xv[j] * wb.x; acc[5] += xv[j] * wb.y;
        acc[6] += xv[j] * wb.z; acc[7] += xv[j] * wb.w;
    }
#pragma unroll
    for (int off = 32; off > 0; off >>= 1) {
#pragma unroll
        for (int e = 0; e < NE; e++) acc[e] += __shfl_down(acc[e], off);
    }
    if (lane == 0) {
        float l[NE], p[NE];
        float m = -1e30f;
#pragma unroll
        for (int e = 0; e < NE; e++) { l[e] = acc[e] + br[e]; m = fmaxf(m, l[e]); }
        float s = 0.0f;
#pragma unroll
        for (int e = 0; e < NE; e++) { p[e] = expf(l[e] - m); s += p[e]; }
        float inv = 1.0f / s;
#pragma unroll
        for (int e = 0; e < NE; e++) { p[e] *= inv; probs[(size_t)t * NE + e] = p[e]; }
        int i1 = 0;
#pragma unroll
        for (int e = 1; e < NE; e++) if (p[e] > p[i1]) i1 = e;
        int i2 = (i1 == 0) ? 1 : 0;
#pragma unroll
        for (int e = 0; e < NE; e++) if (e != i1 && p[e] > p[i2]) i2 = e;
        float denom = 1.0f / (p[i1] + p[i2]);
        topidx[2 * t]     = i1;
        topidx[2 * t + 1] = i2;
        topw[2 * t]       = p[i1] * denom;
        topw[2 * t + 1]   = p[i2] * denom;
    }
}

// ======== plan: reduce + tile map + loss + scatter (+inverse perm) ====
__global__ __launch_bounds__(256) void plan_k(
    const float* __restrict__ probs, const int* __restrict__ topidx,
    const float* __restrict__ topw,
    int* __restrict__ tile_e, int* __restrict__ tile_b, int* __restrict__ tile_v,
    int* __restrict__ perm, float* __restrict__ pw, int* __restrict__ islot,
    float* __restrict__ loss_out)
{
    int tid = threadIdx.x;
    int lane = tid & 63, wave = tid >> 6;

    float ps[NE];
    int c[NE];
#pragma unroll
    for (int e = 0; e < NE; e++) { ps[e] = 0.0f; c[e] = 0; }
    for (int t = tid; t < NT; t += 256) {
        float4 p0 = *(const float4*)&probs[(size_t)t * NE];
        float4 p1 = *(const float4*)&probs[(size_t)t * NE + 4];
        ps[0] += p0.x; ps[1] += p0.y; ps[2] += p0.z; ps[3] += p0.w;
        ps[4] += p1.x; ps[5] += p1.y; ps[6] += p1.z; ps[7] += p1.w;
    }
    for (int t = tid; t < TSLOTS; t += 256) c[topidx[t]]++;
#pragma unroll
    for (int off = 32; off > 0; off >>= 1) {
#pragma unroll
        for (int e = 0; e < NE; e++) {
            ps[e] += __shfl_down(ps[e], off);
            c[e]  += __shfl_down(c[e], off);
        }
    }
    __shared__ float sps[4][NE];
    __shared__ int sc[4][NE];
    __shared__ int scur[NE];
    if (lane == 0) {
#pragma unroll
        for (int e = 0; e < NE; e++) { sps[wave][e] = ps[e]; sc[wave][e] = c[e]; }
    }
    __syncthreads();
    if (tid == 0) {
        float loss = 0.0f;
        int b = 0, tidx = 0;
        for (int e = 0; e < NE; e++) {
            float pse = sps[0][e] + sps[1][e] + sps[2][e] + sps[3][e];
            int ce = sc[0][e] + sc[1][e] + sc[2][e] + sc[3][e];
            loss += ((float)ce / (float)TSLOTS) * (pse / (float)NT);
            int nt = (ce + TM - 1) / TM;
            scur[e] = b;
            for (int i = 0; i < nt; i++) {
                tile_e[tidx] = e;
                tile_b[tidx] = b + i * TM;
                int v = ce - i * TM;
                tile_v[tidx] = v > TM ? TM : v;
                tidx++;
            }
            b += nt * TM;
        }
        for (; tidx < MAXTILES; tidx++) tile_e[tidx] = -1;
        loss_out[0] = 0.01f * (float)NE * loss;
    }
    __syncthreads();
    for (int t = tid; t < TSLOTS; t += 256) {
        int e = topidx[t];
        int p = atomicAdd(&scur[e], 1);
        perm[p] = t;
        pw[p] = topw[t];
        islot[t] = p;
    }
}

// -------- tiled transpose+convert: src[e][K][N] f32 -> dst[e][N][K] bf16 -----
__global__ __launch_bounds__(256) void convT_k(const float* __restrict__ src,
                                               unsigned short* __restrict__ dst,
                                               int K, int N)
{
    int e = blockIdx.z;
    int n0 = blockIdx.x * 32, k0 = blockIdx.y * 32;
    const float* s = src + (size_t)e * K * N;
    unsigned short* d = dst + (size_t)e * N * K;
    __shared__ float T[32][33];
    int tid = threadIdx.x;
    int r = tid >> 3, c4 = (tid & 7) * 4;
    float4 v = *(const float4*)(s + (size_t)(k0 + r) * N + n0 + c4);
    T[r][c4 + 0] = v.x; T[r][c4 + 1] = v.y; T[r][c4 + 2] = v.z; T[r][c4 + 3] = v.w;
    __syncthreads();
    ushort4 o;
    o.x = f2bf(T[c4 + 0][r]); o.y = f2bf(T[c4 + 1][r]);
    o.z = f2bf(T[c4 + 2][r]); o.w = f2bf(T[c4 + 3][r]);
    *(ushort4*)(d + (size_t)(n0 + r) * K + k0 + c4) = o;
}

// ======== grouped MFMA GEMM1: 64x128 tile, BK=64, XOR-swizzled LDS ========
// LDS layout: row r (64 bf16 = 8 granules of 16B), source granule g stored at
// slot g^(r&7). Staging stays contiguous for global_load_lds; fragment reads
// spread fm-lanes across all 32 banks (2-way = free).
__global__ __launch_bounds__(256) void gemm1_k(
    const unsigned short* __restrict__ xb, const unsigned short* __restrict__ w1t,
    const float* __restrict__ b1,
    const int* __restrict__ tile_e, const int* __restrict__ tile_b,
    const int* __restrict__ tile_v, const int* __restrict__ perm,
    unsigned short* __restrict__ hmid)
{
    int tt = blockIdx.y;
    int e = tile_e[tt];
    if (e < 0) return;
    int p0 = tile_b[tt], nv = tile_v[tt];
    int n0 = blockIdx.x * 128;

    __shared__ unsigned short As[64 * 64];    // 8 KB
    __shared__ unsigned short Bs[128 * 64];   // 16 KB

    int tid = threadIdx.x;
    int lane = tid & 63, wave = tid >> 6;
    int wm = (wave >> 1) * 32, wn = (wave & 1) * 64;

    // staging: flat granule f = tid + i*256; row = f>>3, stored slot = f&7,
    // source granule = slot ^ (row&7)
    int rA = tid >> 3, gs = tid & 7;
    int rA2 = rA + 32;
    int tokA = perm[p0 + ((rA < nv) ? rA : 0)] >> 1;
    int tokA2 = perm[p0 + ((rA2 < nv) ? rA2 : 0)] >> 1;
    const unsigned short* apt1 = xb + (size_t)tokA * HID + (gs ^ (rA & 7)) * 8;
    const unsigned short* apt2 = xb + (size_t)tokA2 * HID + (gs ^ (rA2 & 7)) * 8;
    const unsigned short* bbase = w1t + (size_t)e * INTER * HID;
    const unsigned short* bpt0 = bbase + (size_t)(n0 + rA) * HID + (gs ^ (rA & 7)) * 8;
    const unsigned short* bpt1 = bbase + (size_t)(n0 + rA + 32) * HID + (gs ^ ((rA + 32) & 7)) * 8;
    const unsigned short* bpt2 = bbase + (size_t)(n0 + rA + 64) * HID + (gs ^ ((rA + 64) & 7)) * 8;
    const unsigned short* bpt3 = bbase + (size_t)(n0 + rA + 96) * HID + (gs ^ ((rA + 96) & 7)) * 8;

    f32x4 acc[2][4] = {};
    int fm = lane & 15, fq = lane >> 4;

    for (int k0 = 0; k0 < HID; k0 += BKG) {
        __syncthreads();
        gload16(apt1 + k0, (void*)(As + tid * 8));
        gload16(apt2 + k0, (void*)(As + 2048 + tid * 8));
        gload16(bpt0 + k0, (void*)(Bs + tid * 8));
        gload16(bpt1 + k0, (void*)(Bs + 2048 + tid * 8));
        gload16(bpt2 + k0, (void*)(Bs + 4096 + tid * 8));
        gload16(bpt3 + k0, (void*)(Bs + 6144 + tid * 8));
        __syncthreads();
#pragma unroll
        for (int kk = 0; kk < 2; kk++) {
            bf16x8 af[2], bfr[4];
#pragma unroll
            for (int mt = 0; mt < 2; mt++) {
                int R = wm + mt * 16 + fm;
                int G = (kk * 4 + fq) ^ (R & 7);
                af[mt] = *(const bf16x8*)&As[R * 64 + G * 8];
            }
#pragma unroll
            for (int nt = 0; nt < 4; nt++) {
                int R = wn + nt * 16 + fm;
                int G = (kk * 4 + fq) ^ (R & 7);
                bfr[nt] = *(const bf16x8*)&Bs[R * 64 + G * 8];
            }
#pragma unroll
            for (int mt = 0; mt < 2; mt++)
#pragma unroll
                for (int nt = 0; nt < 4; nt++)
                    acc[mt][nt] = __builtin_amdgcn_mfma_f32_16x16x32_bf16(
                        af[mt], bfr[nt], acc[mt][nt], 0, 0, 0);
        }
    }

    // epilogue: C/D layout col=lane&15, row=(lane>>4)*4+reg. Write ALL rows
    // (padded rows = dup of row0's token; gemm2 reads, combine discards).
    int cn = lane & 15, crb = (lane >> 4) * 4;
#pragma unroll
    for (int mt = 0; mt < 2; mt++) {
#pragma unroll
        for (int r = 0; r < 4; r++) {
            int m = wm + mt * 16 + crb + r;
            size_t rowoff = (size_t)(p0 + m) * INTER;
#pragma unroll
            for (int nt = 0; nt < 4; nt++) {
                int gn = n0 + wn + nt * 16 + cn;
                float vv = acc[mt][nt][r] + b1[e * INTER + gn];
                hmid[rowoff + gn] = f2bf(gelu_fast(vv));
            }
        }
    }
}

// ======== grouped MFMA GEMM2: 64x64 tile, BK=64, kz-split=2, swizzled =======
__global__ __launch_bounds__(256) void gemm2_k(
    const unsigned short* __restrict__ hmid, const unsigned short* __restrict__ w2t,
    const float* __restrict__ b2,
    const int* __restrict__ tile_e, const int* __restrict__ tile_b,
    unsigned short* __restrict__ y)
{
    int tt = blockIdx.y;
    int e = tile_e[tt];
    if (e < 0) return;
    int p0 = tile_b[tt];
    int n0 = blockIdx.x * 64;
    int kz = blockIdx.z;
    int kbeg = kz * (INTER / 2), kend = kbeg + INTER / 2;
    unsigned short* yk = y + (size_t)kz * PSLOTS * HID;

    __shared__ unsigned short As[64 * 64];   // 8 KB
    __shared__ unsigned short Bs[64 * 64];   // 8 KB

    int tid = threadIdx.x;
    int lane = tid & 63, wave = tid >> 6;
    int wm = (wave >> 1) * 32, wn = (wave & 1) * 32;

    int rA = tid >> 3, gs = tid & 7;
    int rA2 = rA + 32;
    const unsigned short* apt1 = hmid + (size_t)(p0 + rA) * INTER + (gs ^ (rA & 7)) * 8;
    const unsigned short* apt2 = hmid + (size_t)(p0 + rA2) * INTER + (gs ^ (rA2 & 7)) * 8;
    const unsigned short* bbase = w2t + (size_t)e * HID * INTER;
    const unsigned short* bpt1 = bbase + (size_t)(n0 + rA) * INTER + (gs ^ (rA & 7)) * 8;
    const unsigned short* bpt2 = bbase + (size_t)(n0 + rA2) * INTER + (gs ^ (rA2 & 7)) * 8;

    f32x4 acc[2][2] = {};
    int fm = lane & 15, fq = lane >> 4;

    for (int k0 = kbeg; k0 < kend; k0 += BKG) {
        __syncthreads();
        gload16(apt1 + k0, (void*)(As + tid * 8));
        gload16(apt2 + k0, (void*)(As + 2048 + tid * 8));
        gload16(bpt1 + k0, (void*)(Bs + tid * 8));
        gload16(bpt2 + k0, (void*)(Bs + 2048 + tid * 8));
        __syncthreads();
#pragma unroll
        for (int kk = 0; kk < 2; kk++) {
            bf16x8 af[2], bfr[2];
#pragma unroll
            for (int mt = 0; mt < 2; mt++) {
                int R = wm + mt * 16 + fm;
                int G = (kk * 4 + fq) ^ (R & 7);
                af[mt] = *(const bf16x8*)&As[R * 64 + G * 8];
            }
#pragma unroll
            for (int nt = 0; nt < 2; nt++) {
                int R = wn + nt * 16 + fm;
                int G = (kk * 4 + fq) ^ (R & 7);
                bfr[nt] = *(const bf16x8*)&Bs[R * 64 + G * 8];
            }
#pragma unroll
            for (int mt = 0; mt < 2; mt++)
#pragma unroll
                for (int nt = 0; nt < 2; nt++)
                    acc[mt][nt] = __builtin_amdgcn_mfma_f32_16x16x32_bf16(
                        af[mt], bfr[nt], acc[mt][nt], 0, 0, 0);
        }
    }

    int cn = lane & 15, crb = (lane >> 4) * 4;
#pragma unroll
    for (int mt = 0; mt < 2; mt++) {
#pragma unroll
        for (int r = 0; r < 4; r++) {
            int m = wm + mt * 16 + crb + r;
            size_t rowoff = (size_t)(p0 + m) * HID;
#pragma unroll
            for (int nt = 0; nt < 2; nt++) {
                int gn = n0 + wn + nt * 16 + cn;
                float bias = (kz == 0) ? b2[e * HID + gn] : 0.0f;
                yk[rowoff + gn] = f2bf(acc[mt][nt][r] + bias);
            }
        }
    }
}

// ======== combine: out = hs + wA*(y0[pA]+y1[pA]) + wB*(y0[pB]+y1[pB]) ========
__global__ __launch_bounds__(64) void combine_k(
    const float* __restrict__ hs, const unsigned short* __restrict__ y,
    const int* __restrict__ islot, const float* __restrict__ pw,
    float* __restrict__ out)
{
    int t = blockIdx.x;
    int lane = threadIdx.x;
    int pA = islot[2 * t], pB = islot[2 * t + 1];
    float wA = pw[pA], wB = pw[pB];
    int c = lane * 8;
    const unsigned short* yA0 = y + (size_t)pA * HID + c;
    const unsigned short* yB0 = y + (size_t)pB * HID + c;
    const unsigned short* yA1 = yA0 + (size_t)PSLOTS * HID;
    const unsigned short* yB1 = yB0 + (size_t)PSLOTS * HID;
    ushort8 a0 = *(const ushort8*)yA0;
    ushort8 a1 = *(const ushort8*)yA1;
    ushort8 b0 = *(const ushort8*)yB0;
    ushort8 b1 = *(const ushort8*)yB1;
    const float* h = hs + (size_t)t * HID + c;
    float4 h0 = *(const float4*)h;
    float4 h1 = *(const float4*)(h + 4);
    float o[8];
#pragma unroll
    for (int j = 0; j < 8; j++)
        o[j] = wA * (bf2f(a0[j]) + bf2f(a1[j])) + wB * (bf2f(b0[j]) + bf2f(b1[j]));
    float4 r0 = {o[0] + h0.x, o[1] + h0.y, o[2] + h0.z, o[3] + h0.w};
    float4 r1 = {o[4] + h1.x, o[5] + h1.y, o[6] + h1.z, o[7] + h1.w};
    float* op = out + (size_t)t * HID + c;
    *(float4*)op = r0;
    *(float4*)(op + 4) = r1;
}

extern "C" void kernel_launch(void* const* d_in, const int* in_sizes, int n_in,
                              void* d_out, int out_size, void* d_ws, size_t ws_size,
                              hipStream_t stream) {
    const float* hs = (const float*)d_in[0];
    const float* wr = (const float*)d_in[1];
    const float* br = (const float*)d_in[2];
    const float* w1 = (const float*)d_in[3];
    const float* b1 = (const float*)d_in[4];
    const float* w2 = (const float*)d_in[5];
    const float* b2 = (const float*)d_in[6];
    float* out = (float*)d_out;

    char* ws = (char*)d_ws;
    float* probs           = (float*)(ws + WS_PROBS);
    int*   topidx          = (int*)(ws + WS_TOPIDX);
    float* topw            = (float*)(ws + WS_TOPW);
    int*   tile_e          = (int*)(ws + WS_TILE_E);
    int*   tile_b          = (int*)(ws + WS_TILE_B);
    int*   tile_v          = (int*)(ws + WS_TILE_V);
    int*   perm            = (int*)(ws + WS_PERM);
    float* pw              = (float*)(ws + WS_PW);
    int*   islot           = (int*)(ws + WS_ISLOT);
    unsigned short* xb     = (unsigned short*)(ws + WS_XB);
    unsigned short* wt     = (unsigned short*)(ws + WS_WT);
    unsigned short* hmid   = (unsigned short*)(ws + WS_HMID);
    unsigned short* y      = (unsigned short*)(ws + WS_Y);

    route_k<<<NT, 64, 0, stream>>>(hs, wr, br, xb, probs, topidx, topw);
    plan_k<<<1, 256, 0, stream>>>(probs, topidx, topw, tile_e, tile_b, tile_v,
                                  perm, pw, islot, out + (size_t)NT * HID);
    convT_k<<<dim3(INTER / 32, HID / 32, NE), 256, 0, stream>>>(w1, wt, HID, INTER);
    gemm1_k<<<dim3(INTER / 128, MAXTILES), 256, 0, stream>>>(
        xb, wt, b1, tile_e, tile_b, tile_v, perm, hmid);
    convT_k<<<dim3(HID / 32, INTER / 32, NE), 256, 0, stream>>>(w2, wt, INTER, HID);
    gemm2_k<<<dim3(HID / 64, MAXTILES, 2), 256, 0, stream>>>(
        hmid, wt, b2, tile_e, tile_b, y);
    combine_k<<<NT, 64, 0, stream>>>(hs, y, islot, pw, out);
}

// Round 7
// 189.674 us; speedup vs baseline: 2.5427x; 1.0176x over previous
//
#include <hip/hip_runtime.h>
#include <math.h>

#define NT 2048       // tokens (B*S)
#define TSLOTS 4096   // token-slots (NT*K)
#define HID 512
#define INTER 2048
#define NE 8
#define TM 64         // row-tile (bucket alignment)
#define BKG 64        // k-tile
#define MAXTILES 72   // sum ceil(cnt_e/64) <= 4096/64 + 7
#define PSLOTS 4608   // padded slot capacity
#define ROUTE_BLOCKS 512   // 4 tokens per block

// ---------------- workspace layout (bytes) ----------------
#define WS_HMID      0          // PSLOTS*INTER ushort = 18874368
#define WS_PROBS     0          // NT*NE floats (dead after plan_k)
#define WS_TOPIDX    65536      // TSLOTS ints  (dead after plan_k)
#define WS_TOPW      81920      // TSLOTS floats (dead after plan_k)
#define WS_TILE_E    18874368
#define WS_TILE_B    18874880
#define WS_TILE_V    18875392
#define WS_PERM      18875904   // PSLOTS ints
#define WS_PW        18894336
#define WS_ISLOT     18912768
#define WS_XB        18929152   // NT*HID ushort = 2097152
#define WS_W1T       21026304   // 16777216
#define WS_W2T       37803520   // 16777216
#define WS_Y         54580736   // 2 * PSLOTS*HID ushort = 9437184 (end ~64MB)

typedef __attribute__((ext_vector_type(8))) short bf16x8;
typedef __attribute__((ext_vector_type(4))) float f32x4;
typedef __attribute__((ext_vector_type(8))) unsigned short ushort8;

__device__ __forceinline__ unsigned short f2bf(float f) {
    union { float f; unsigned u; } v; v.f = f;
    unsigned r = v.u + 0x7FFF + ((v.u >> 16) & 1);   // RNE
    return (unsigned short)(r >> 16);
}
__device__ __forceinline__ float bf2f(unsigned short b) {
    union { unsigned u; float f; } v; v.u = ((unsigned)b) << 16;
    return v.f;
}

__device__ __forceinline__ void gload16(const void* g, void* l) {
    __builtin_amdgcn_global_load_lds(
        (const __attribute__((address_space(1))) unsigned int*)g,
        (__attribute__((address_space(3))) unsigned int*)l, 16, 0, 0);
}

// gelu_tanh(x) == x * sigmoid(2*0.7978845608*(x + 0.044715 x^3))  (exact identity)
__device__ __forceinline__ float gelu_fast(float x) {
    float t = 1.5957691f * x + 0.0713548f * x * x * x;
    return x / (1.0f + __expf(-t));
}

// ======== pre: router (4 tokens/block) + both weight transposes, one launch ==
__global__ __launch_bounds__(256) void pre_k(
    const float* __restrict__ hs, const float* __restrict__ wr,
    const float* __restrict__ br,
    const float* __restrict__ w1, const float* __restrict__ w2,
    unsigned short* __restrict__ xb,
    unsigned short* __restrict__ w1t, unsigned short* __restrict__ w2t,
    float* __restrict__ probs, int* __restrict__ topidx, float* __restrict__ topw)
{
    __shared__ float T[32][33];
    int bx = blockIdx.x;
    int tid = threadIdx.x;

    if (bx < ROUTE_BLOCKS) {
        int lane = tid & 63, wave = tid >> 6;
        int t = bx * 4 + wave;
        const float* x = hs + (size_t)t * HID + lane * 8;
        float4 v0 = *(const float4*)x;
        float4 v1 = *(const float4*)(x + 4);

        ushort8 ob;
        ob[0] = f2bf(v0.x); ob[1] = f2bf(v0.y); ob[2] = f2bf(v0.z); ob[3] = f2bf(v0.w);
        ob[4] = f2bf(v1.x); ob[5] = f2bf(v1.y); ob[6] = f2bf(v1.z); ob[7] = f2bf(v1.w);
        *(ushort8*)(xb + (size_t)t * HID + lane * 8) = ob;

        float xv[8] = {v0.x, v0.y, v0.z, v0.w, v1.x, v1.y, v1.z, v1.w};
        float acc[NE];
#pragma unroll
        for (int e = 0; e < NE; e++) acc[e] = 0.0f;
        const float* w = wr + (size_t)lane * 8 * NE;
#pragma unroll
        for (int j = 0; j < 8; j++) {
            float4 wa = *(const float4*)(w + j * NE);
            float4 wb = *(const float4*)(w + j * NE + 4);
            acc[0] += xv[j] * wa.x; acc[1] += xv[j] * wa.y;
            acc[2] += xv[j] * wa.z; acc[3] += xv[j] * wa.w;
            acc[4] += xv[j] * wb.x; acc[5] += xv[j] * wb.y;
            acc[6] += xv[j] * wb.z; acc[7] += xv[j] * wb.w;
        }
#pragma unroll
        for (int off = 32; off > 0; off >>= 1) {
#pragma unroll
            for (int e = 0; e < NE; e++) acc[e] += __shfl_down(acc[e], off);
        }
        if (lane == 0) {
            float l[NE], p[NE];
            float m = -1e30f;
#pragma unroll
            for (int e = 0; e < NE; e++) { l[e] = acc[e] + br[e]; m = fmaxf(m, l[e]); }
            float s = 0.0f;
#pragma unroll
            for (int e = 0; e < NE; e++) { p[e] = expf(l[e] - m); s += p[e]; }
            float inv = 1.0f / s;
#pragma unroll
            for (int e = 0; e < NE; e++) { p[e] *= inv; probs[(size_t)t * NE + e] = p[e]; }
            int i1 = 0;
#pragma unroll
            for (int e = 1; e < NE; e++) if (p[e] > p[i1]) i1 = e;
            int i2 = (i1 == 0) ? 1 : 0;
#pragma unroll
            for (int e = 0; e < NE; e++) if (e != i1 && p[e] > p[i2]) i2 = e;
            float denom = 1.0f / (p[i1] + p[i2]);
            topidx[2 * t]     = i1;
            topidx[2 * t + 1] = i2;
            topw[2 * t]       = p[i1] * denom;
            topw[2 * t + 1]   = p[i2] * denom;
        }
        return;
    }

    // ---- weight transpose+convert: 32x32 tiles ----
    int t = bx - ROUTE_BLOCKS;
    const float* src;
    unsigned short* dst;
    int K, N, n0, k0;
    if (t < 8192) {            // w1: [e][K=512][N=2048] -> w1t [e][N][K]
        int e = t >> 10, rem = t & 1023;
        n0 = (rem & 63) * 32; k0 = (rem >> 6) * 32;
        src = w1 + (size_t)e * HID * INTER;
        dst = w1t + (size_t)e * INTER * HID;
        K = HID; N = INTER;
    } else {                   // w2: [e][K=2048][N=512] -> w2t [e][N][K]
        t -= 8192;
        int e = t >> 10, rem = t & 1023;
        n0 = (rem & 15) * 32; k0 = (rem >> 4) * 32;
        src = w2 + (size_t)e * INTER * HID;
        dst = w2t + (size_t)e * HID * INTER;
        K = INTER; N = HID;
    }
    int r = tid >> 3, c4 = (tid & 7) * 4;
    float4 v = *(const float4*)(src + (size_t)(k0 + r) * N + n0 + c4);
    T[r][c4 + 0] = v.x; T[r][c4 + 1] = v.y; T[r][c4 + 2] = v.z; T[r][c4 + 3] = v.w;
    __syncthreads();
    ushort4 o;
    o.x = f2bf(T[c4 + 0][r]); o.y = f2bf(T[c4 + 1][r]);
    o.z = f2bf(T[c4 + 2][r]); o.w = f2bf(T[c4 + 3][r]);
    *(ushort4*)(dst + (size_t)(n0 + r) * K + k0 + c4) = o;
}

// ======== plan: reduce + tile map + loss + scatter (+inverse perm) ====
__global__ __launch_bounds__(256) void plan_k(
    const float* __restrict__ probs, const int* __restrict__ topidx,
    const float* __restrict__ topw,
    int* __restrict__ tile_e, int* __restrict__ tile_b, int* __restrict__ tile_v,
    int* __restrict__ perm, float* __restrict__ pw, int* __restrict__ islot,
    float* __restrict__ loss_out)
{
    int tid = threadIdx.x;
    int lane = tid & 63, wave = tid >> 6;

    float ps[NE];
    int c[NE];
#pragma unroll
    for (int e = 0; e < NE; e++) { ps[e] = 0.0f; c[e] = 0; }
    for (int t = tid; t < NT; t += 256) {
        float4 p0 = *(const float4*)&probs[(size_t)t * NE];
        float4 p1 = *(const float4*)&probs[(size_t)t * NE + 4];
        ps[0] += p0.x; ps[1] += p0.y; ps[2] += p0.z; ps[3] += p0.w;
        ps[4] += p1.x; ps[5] += p1.y; ps[6] += p1.z; ps[7] += p1.w;
    }
    for (int t = tid; t < TSLOTS; t += 256) c[topidx[t]]++;
#pragma unroll
    for (int off = 32; off > 0; off >>= 1) {
#pragma unroll
        for (int e = 0; e < NE; e++) {
            ps[e] += __shfl_down(ps[e], off);
            c[e]  += __shfl_down(c[e], off);
        }
    }
    __shared__ float sps[4][NE];
    __shared__ int sc[4][NE];
    __shared__ int scur[NE], sbase[NE], scnt[NE], spref[NE + 1];
    if (lane == 0) {
#pragma unroll
        for (int e = 0; e < NE; e++) { sps[wave][e] = ps[e]; sc[wave][e] = c[e]; }
    }
    __syncthreads();
    if (tid == 0) {
        float loss = 0.0f;
        int b = 0, tp = 0;
        for (int e = 0; e < NE; e++) {
            float pse = sps[0][e] + sps[1][e] + sps[2][e] + sps[3][e];
            int ce = sc[0][e] + sc[1][e] + sc[2][e] + sc[3][e];
            loss += ((float)ce / (float)TSLOTS) * (pse / (float)NT);
            int nt = (ce + TM - 1) / TM;
            sbase[e] = b; scnt[e] = ce; scur[e] = b; spref[e] = tp;
            tp += nt;
            b += nt * TM;
        }
        spref[NE] = tp;
        loss_out[0] = 0.01f * (float)NE * loss;
    }
    __syncthreads();
    // parallel tile map
    for (int tx = tid; tx < MAXTILES; tx += 256) {
        if (tx >= spref[NE]) { tile_e[tx] = -1; continue; }
        int e = 0;
        while (tx >= spref[e + 1]) e++;
        int i = tx - spref[e];
        tile_e[tx] = e;
        tile_b[tx] = sbase[e] + i * TM;
        int v = scnt[e] - i * TM;
        tile_v[tx] = v > TM ? TM : v;
    }
    __syncthreads();
    for (int t = tid; t < TSLOTS; t += 256) {
        int e = topidx[t];
        int p = atomicAdd(&scur[e], 1);
        perm[p] = t;
        pw[p] = topw[t];
        islot[t] = p;
    }
}

// ======== grouped MFMA GEMM1: 64x128 tile, BK=64, swizzled, C^T epilogue =====
// mfma(bfr, af, acc): D rows <- n (4 consecutive per reg quad), cols <- m.
// Enables ushort4 stores + float4 bias loads.
__global__ __launch_bounds__(256) void gemm1_k(
    const unsigned short* __restrict__ xb, const unsigned short* __restrict__ w1t,
    const float* __restrict__ b1,
    const int* __restrict__ tile_e, const int* __restrict__ tile_b,
    const int* __restrict__ tile_v, const int* __restrict__ perm,
    unsigned short* __restrict__ hmid)
{
    int tt = blockIdx.y;
    int e = tile_e[tt];
    if (e < 0) return;
    int p0 = tile_b[tt], nv = tile_v[tt];
    int n0 = blockIdx.x * 128;

    __shared__ unsigned short As[64 * 64];    // 8 KB
    __shared__ unsigned short Bs[128 * 64];   // 16 KB

    int tid = threadIdx.x;
    int lane = tid & 63, wave = tid >> 6;
    int wm = (wave >> 1) * 32, wn = (wave & 1) * 64;

    int rA = tid >> 3, gs = tid & 7;
    int rA2 = rA + 32;
    int tokA = perm[p0 + ((rA < nv) ? rA : 0)] >> 1;
    int tokA2 = perm[p0 + ((rA2 < nv) ? rA2 : 0)] >> 1;
    const unsigned short* apt1 = xb + (size_t)tokA * HID + (gs ^ (rA & 7)) * 8;
    const unsigned short* apt2 = xb + (size_t)tokA2 * HID + (gs ^ (rA2 & 7)) * 8;
    const unsigned short* bbase = w1t + (size_t)e * INTER * HID;
    const unsigned short* bpt0 = bbase + (size_t)(n0 + rA) * HID + (gs ^ (rA & 7)) * 8;
    const unsigned short* bpt1 = bbase + (size_t)(n0 + rA + 32) * HID + (gs ^ ((rA + 32) & 7)) * 8;
    const unsigned short* bpt2 = bbase + (size_t)(n0 + rA + 64) * HID + (gs ^ ((rA + 64) & 7)) * 8;
    const unsigned short* bpt3 = bbase + (size_t)(n0 + rA + 96) * HID + (gs ^ ((rA + 96) & 7)) * 8;

    f32x4 acc[2][4] = {};
    int fm = lane & 15, fq = lane >> 4;

    for (int k0 = 0; k0 < HID; k0 += BKG) {
        __syncthreads();
        gload16(apt1 + k0, (void*)(As + tid * 8));
        gload16(apt2 + k0, (void*)(As + 2048 + tid * 8));
        gload16(bpt0 + k0, (void*)(Bs + tid * 8));
        gload16(bpt1 + k0, (void*)(Bs + 2048 + tid * 8));
        gload16(bpt2 + k0, (void*)(Bs + 4096 + tid * 8));
        gload16(bpt3 + k0, (void*)(Bs + 6144 + tid * 8));
        __syncthreads();
#pragma unroll
        for (int kk = 0; kk < 2; kk++) {
            bf16x8 af[2], bfr[4];
#pragma unroll
            for (int mt = 0; mt < 2; mt++) {
                int R = wm + mt * 16 + fm;
                int G = (kk * 4 + fq) ^ (R & 7);
                af[mt] = *(const bf16x8*)&As[R * 64 + G * 8];
            }
#pragma unroll
            for (int nt = 0; nt < 4; nt++) {
                int R = wn + nt * 16 + fm;
                int G = (kk * 4 + fq) ^ (R & 7);
                bfr[nt] = *(const bf16x8*)&Bs[R * 64 + G * 8];
            }
#pragma unroll
            for (int mt = 0; mt < 2; mt++)
#pragma unroll
                for (int nt = 0; nt < 4; nt++)
                    acc[mt][nt] = __builtin_amdgcn_mfma_f32_16x16x32_bf16(
                        bfr[nt], af[mt], acc[mt][nt], 0, 0, 0);
        }
    }

    // epilogue: row(n) = quad*4+reg, col(m) = lane&15 (operand-swapped C^T)
    int cm = lane & 15, qn = (lane >> 4) * 4;
#pragma unroll
    for (int mt = 0; mt < 2; mt++) {
        int m = wm + mt * 16 + cm;
        size_t rowoff = (size_t)(p0 + m) * INTER;
#pragma unroll
        for (int nt = 0; nt < 4; nt++) {
            int nb = n0 + wn + nt * 16 + qn;
            float4 bb = *(const float4*)(b1 + e * INTER + nb);
            ushort4 o;
            o.x = f2bf(gelu_fast(acc[mt][nt][0] + bb.x));
            o.y = f2bf(gelu_fast(acc[mt][nt][1] + bb.y));
            o.z = f2bf(gelu_fast(acc[mt][nt][2] + bb.z));
            o.w = f2bf(gelu_fast(acc[mt][nt][3] + bb.w));
            *(ushort4*)(hmid + rowoff + nb) = o;
        }
    }
}

// ======== grouped MFMA GEMM2: 64x64 tile, BK=64, kz=2, swizzled, C^T epi =====
__global__ __launch_bounds__(256) void gemm2_k(
    const unsigned short* __restrict__ hmid, const unsigned short* __restrict__ w2t,
    const float* __restrict__ b2,
    const int* __restrict__ tile_e, const int* __restrict__ tile_b,
    unsigned short* __restrict__ y)
{
    int tt = blockIdx.y;
    int e = tile_e[tt];
    if (e < 0) return;
    int p0 = tile_b[tt];
    int n0 = blockIdx.x * 64;
    int kz = blockIdx.z;
    int kbeg = kz * (INTER / 2), kend = kbeg + INTER / 2;
    unsigned short* yk = y + (size_t)kz * PSLOTS * HID;

    __shared__ unsigned short As[64 * 64];   // 8 KB
    __shared__ unsigned short Bs[64 * 64];   // 8 KB

    int tid = threadIdx.x;
    int lane = tid & 63, wave = tid >> 6;
    int wm = (wave >> 1) * 32, wn = (wave & 1) * 32;

    int rA = tid >> 3, gs = tid & 7;
    int rA2 = rA + 32;
    const unsigned short* apt1 = hmid + (size_t)(p0 + rA) * INTER + (gs ^ (rA & 7)) * 8;
    const unsigned short* apt2 = hmid + (size_t)(p0 + rA2) * INTER + (gs ^ (rA2 & 7)) * 8;
    const unsigned short* bbase = w2t + (size_t)e * HID * INTER;
    const unsigned short* bpt1 = bbase + (size_t)(n0 + rA) * INTER + (gs ^ (rA & 7)) * 8;
    const unsigned short* bpt2 = bbase + (size_t)(n0 + rA2) * INTER + (gs ^ (rA2 & 7)) * 8;

    f32x4 acc[2][2] = {};
    int fm = lane & 15, fq = lane >> 4;

    for (int k0 = kbeg; k0 < kend; k0 += BKG) {
        __syncthreads();
        gload16(apt1 + k0, (void*)(As + tid * 8));
        gload16(apt2 + k0, (void*)(As + 2048 + tid * 8));
        gload16(bpt1 + k0, (void*)(Bs + tid * 8));
        gload16(bpt2 + k0, (void*)(Bs + 2048 + tid * 8));
        __syncthreads();
#pragma unroll
        for (int kk = 0; kk < 2; kk++) {
            bf16x8 af[2], bfr[2];
#pragma unroll
            for (int mt = 0; mt < 2; mt++) {
                int R = wm + mt * 16 + fm;
                int G = (kk * 4 + fq) ^ (R & 7);
                af[mt] = *(const bf16x8*)&As[R * 64 + G * 8];
            }
#pragma unroll
            for (int nt = 0; nt < 2; nt++) {
                int R = wn + nt * 16 + fm;
                int G = (kk * 4 + fq) ^ (R & 7);
                bfr[nt] = *(const bf16x8*)&Bs[R * 64 + G * 8];
            }
#pragma unroll
            for (int mt = 0; mt < 2; mt++)
#pragma unroll
                for (int nt = 0; nt < 2; nt++)
                    acc[mt][nt] = __builtin_amdgcn_mfma_f32_16x16x32_bf16(
                        bfr[nt], af[mt], acc[mt][nt], 0, 0, 0);
        }
    }

    int cm = lane & 15, qn = (lane >> 4) * 4;
#pragma unroll
    for (int mt = 0; mt < 2; mt++) {
        int m = wm + mt * 16 + cm;
        size_t rowoff = (size_t)(p0 + m) * HID;
#pragma unroll
        for (int nt = 0; nt < 2; nt++) {
            int nb = n0 + wn + nt * 16 + qn;
            float4 bb = (kz == 0) ? *(const float4*)(b2 + e * HID + nb)
                                  : float4{0.0f, 0.0f, 0.0f, 0.0f};
            ushort4 o;
            o.x = f2bf(acc[mt][nt][0] + bb.x);
            o.y = f2bf(acc[mt][nt][1] + bb.y);
            o.z = f2bf(acc[mt][nt][2] + bb.z);
            o.w = f2bf(acc[mt][nt][3] + bb.w);
            *(ushort4*)(yk + rowoff + nb) = o;
        }
    }
}

// ======== combine: out = hs + wA*(y0[pA]+y1[pA]) + wB*(y0[pB]+y1[pB]) ========
__global__ __launch_bounds__(256) void combine_k(
    const float* __restrict__ hs, const unsigned short* __restrict__ y,
    const int* __restrict__ islot, const float* __restrict__ pw,
    float* __restrict__ out)
{
    int tid = threadIdx.x;
    int lane = tid & 63, wave = tid >> 6;
    int t = blockIdx.x * 4 + wave;
    int pA = islot[2 * t], pB = islot[2 * t + 1];
    float wA = pw[pA], wB = pw[pB];
    int c = lane * 8;
    const unsigned short* yA0 = y + (size_t)pA * HID + c;
    const unsigned short* yB0 = y + (size_t)pB * HID + c;
    const unsigned short* yA1 = yA0 + (size_t)PSLOTS * HID;
    const unsigned short* yB1 = yB0 + (size_t)PSLOTS * HID;
    ushort8 a0 = *(const ushort8*)yA0;
    ushort8 a1 = *(const ushort8*)yA1;
    ushort8 b0 = *(const ushort8*)yB0;
    ushort8 b1 = *(const ushort8*)yB1;
    const float* h = hs + (size_t)t * HID + c;
    float4 h0 = *(const float4*)h;
    float4 h1 = *(const float4*)(h + 4);
    float o[8];
#pragma unroll
    for (int j = 0; j < 8; j++)
        o[j] = wA * (bf2f(a0[j]) + bf2f(a1[j])) + wB * (bf2f(b0[j]) + bf2f(b1[j]));
    float4 r0 = {o[0] + h0.x, o[1] + h0.y, o[2] + h0.z, o[3] + h0.w};
    float4 r1 = {o[4] + h1.x, o[5] + h1.y, o[6] + h1.z, o[7] + h1.w};
    float* op = out + (size_t)t * HID + c;
    *(float4*)op = r0;
    *(float4*)(op + 4) = r1;
}

extern "C" void kernel_launch(void* const* d_in, const int* in_sizes, int n_in,
                              void* d_out, int out_size, void* d_ws, size_t ws_size,
                              hipStream_t stream) {
    const float* hs = (const float*)d_in[0];
    const float* wr = (const float*)d_in[1];
    const float* br = (const float*)d_in[2];
    const float* w1 = (const float*)d_in[3];
    const float* b1 = (const float*)d_in[4];
    const float* w2 = (const float*)d_in[5];
    const float* b2 = (const float*)d_in[6];
    float* out = (float*)d_out;

    char* ws = (char*)d_ws;
    float* probs           = (float*)(ws + WS_PROBS);
    int*   topidx          = (int*)(ws + WS_TOPIDX);
    float* topw            = (float*)(ws + WS_TOPW);
    int*   tile_e          = (int*)(ws + WS_TILE_E);
    int*   tile_b          = (int*)(ws + WS_TILE_B);
    int*   tile_v          = (int*)(ws + WS_TILE_V);
    int*   perm            = (int*)(ws + WS_PERM);
    float* pw              = (float*)(ws + WS_PW);
    int*   islot           = (int*)(ws + WS_ISLOT);
    unsigned short* xb     = (unsigned short*)(ws + WS_XB);
    unsigned short* w1t    = (unsigned short*)(ws + WS_W1T);
    unsigned short* w2t    = (unsigned short*)(ws + WS_W2T);
    unsigned short* hmid   = (unsigned short*)(ws + WS_HMID);
    unsigned short* y      = (unsigned short*)(ws + WS_Y);

    pre_k<<<ROUTE_BLOCKS + 16384, 256, 0, stream>>>(
        hs, wr, br, w1, w2, xb, w1t, w2t, probs, topidx, topw);
    plan_k<<<1, 256, 0, stream>>>(probs, topidx, topw, tile_e, tile_b, tile_v,
                                  perm, pw, islot, out + (size_t)NT * HID);
    gemm1_k<<<dim3(INTER / 128, MAXTILES), 256, 0, stream>>>(
        xb, w1t, b1, tile_e, tile_b, tile_v, perm, hmid);
    gemm2_k<<<dim3(HID / 64, MAXTILES, 2), 256, 0, stream>>>(
        hmid, w2t, b2, tile_e, tile_b, y);
    combine_k<<<NT / 4, 256, 0, stream>>>(hs, y, islot, pw, out);
}